// Round 7
// baseline (1121.301 us; speedup 1.0000x reference)
//
#include <hip/hip_runtime.h>

typedef _Float16 f16;
typedef unsigned int u32;
typedef f16 f16x8 __attribute__((ext_vector_type(8)));
typedef f16 f16x4 __attribute__((ext_vector_type(4)));
typedef float f32x4 __attribute__((ext_vector_type(4)));

// N=4,T=8,H=64,W=64,C=512, WS=8, heads=8, head_dim=64
// windows = 2048, tokens/window = 64, M = 131072, K = 512, Nqkv = 1536

__device__ __forceinline__ int src_row(int m) {
    int win = m >> 6, s = m & 63;
    return ((win >> 6) << 12) | (((win >> 3) & 7) << 9) | ((s >> 3) << 6) |
           ((win & 7) << 3) | (s & 7);
}

__device__ __forceinline__ void gload_lds16(const void* g, void* lds) {
    __builtin_amdgcn_global_load_lds(
        (const __attribute__((address_space(1))) u32*)g,
        (__attribute__((address_space(3))) u32*)lds, 16, 0, 0);
}

// ---------------- prep: weights fp32 -> fp16 ----------------
__global__ __launch_bounds__(256) void prep_weights_k(
        const float* __restrict__ Wi, const float* __restrict__ Wo,
        f16* __restrict__ Wi_h, f16* __restrict__ Wo_h) {
    int i = blockIdx.x * 256 + threadIdx.x;    // 262144 float4s total
    const float4* src;
    f16* dst;
    int idx;
    if (i < 196608) { src = (const float4*)Wi; dst = Wi_h; idx = i; }
    else            { src = (const float4*)Wo; dst = Wo_h; idx = i - 196608; }
    float4 v = src[idx];
    f16x4 h = {(f16)v.x, (f16)v.y, (f16)v.z, (f16)v.w};
    *(f16x4*)(dst + (size_t)idx * 4) = h;
}

// ---------------- prep: biasT[s][o] = b_in[o] + (o<1024 ? pos[s]·W_in[o] : 0)
__global__ __launch_bounds__(256) void prep_bias_k(
        const float* __restrict__ pos, const float* __restrict__ Wi,
        const float* __restrict__ b_in, float* __restrict__ biasT) {
    int idx = blockIdx.x * 256 + threadIdx.x;   // 64*1536
    int s = idx / 1536, o = idx % 1536;
    float acc = b_in[o];
    if (o < 1024) {
        const float4* p4 = (const float4*)(pos + (size_t)s * 512);
        const float4* w4 = (const float4*)(Wi + (size_t)o * 512);
        #pragma unroll 4
        for (int c = 0; c < 128; ++c) {
            float4 a = p4[c], b = w4[c];
            acc += a.x * b.x + a.y * b.y + a.z * b.z + a.w * b.w;
        }
    }
    biasT[idx] = acc;
}

// ---------------- prep: x fp32 -> window-major f16 ----------------
__global__ __launch_bounds__(256) void prep_x_k(
        const float* __restrict__ x, f16* __restrict__ xh, int m0) {
    int i = blockIdx.x * 256 + threadIdx.x;    // Mc*64
    int ml = i >> 6, c8 = (i & 63) * 8;
    int sr = src_row(m0 + ml);
    const float4* s4 = (const float4*)(x + (size_t)sr * 512 + c8);
    float4 a = s4[0], b = s4[1];
    f16x8 hv = {(f16)a.x, (f16)a.y, (f16)a.z, (f16)a.w,
                (f16)b.x, (f16)b.y, (f16)b.z, (f16)b.w};
    *(f16x8*)(xh + (size_t)ml * 512 + c8) = hv;
}

// ---------------- QKV GEMM: 256-wide tiles, BK=64, 8-phase counted-vmcnt,
// MULTI-PANEL: each block runs 4 consecutive M-panels (NT=32 tiles, one prologue,
// pipeline never drains at panel boundaries; epilogue stores overlap next panel).
__global__ void __launch_bounds__(512, 2) qkv_gemm8_k(
        const f16* __restrict__ xh, const f16* __restrict__ Wh,
        const float* __restrict__ biasT, f16* __restrict__ qk,
        f16* __restrict__ vT, int nblk) {
    extern __shared__ f16 lds[];
    int tid = threadIdx.x;
    int lane = tid & 63, wid = tid >> 6;
    int l15 = lane & 15, g = lane >> 4;
    int wm = wid >> 2, wn = wid & 3;            // 2M x 4N waves, wave tile 128x64
    int sid = (blockIdx.x & 7) * (nblk >> 3) + (blockIdx.x >> 3);
    int bmg = sid / 6, bn = sid % 6;            // bmg: group of 4 M-panels
    const f16* Ap = xh + (size_t)bmg * 4 * 256 * 512;
    const f16* Bp = Wh + (size_t)bn * 256 * 512;

    int li0 = tid, li1 = tid + 512;
    int r0 = li0 >> 3, c0 = li0 & 7, r1 = li1 >> 3, c1 = li1 & 7;
    int off0 = r0 * 512 + ((c0 ^ (r0 & 7)) * 8);
    int off1 = r1 * 512 + ((c1 ^ (r1 & 7)) * 8);

    // Tabs: absolute tile index 0..31. A panel = Tabs>>3, within-panel tile = Tabs&7.
    auto stageA = [&](int Tabs, int h) {
        int dst = ((Tabs & 1) * 2 + h) * 8192 + wid * 512;
        const f16* src = Ap + (size_t)(Tabs >> 3) * 131072 + h * 65536 + (Tabs & 7) * 64;
        gload_lds16(src + off0, (void*)&lds[dst]);
        gload_lds16(src + off1, (void*)&lds[dst + 4096]);
    };
    auto stageB = [&](int Tabs, int h) {
        int dst = 32768 + ((Tabs & 1) * 2 + h) * 8192 + wid * 512;
        const f16* src = Bp + h * 65536 + (Tabs & 7) * 64;
        gload_lds16(src + off0, (void*)&lds[dst]);
        gload_lds16(src + off1, (void*)&lds[dst + 4096]);
    };

    f32x4 acc[8][4];
    f32x4 zero4 = {0.f, 0.f, 0.f, 0.f};
    #pragma unroll
    for (int a = 0; a < 8; ++a)
        #pragma unroll
        for (int b = 0; b < 4; ++b) acc[a][b] = zero4;
    f16x8 bf[4][2];

    stageA(0, 0); stageA(0, 1); stageB(0, 0); stageB(0, 1);
    stageA(1, 0); stageA(1, 1); stageB(1, 0); stageB(1, 1);
    asm volatile("s_waitcnt vmcnt(8)" ::: "memory");   // tile0 landed; tile1 in flight
    __builtin_amdgcn_s_barrier();

    for (int p = 0; p < 4; ++p) {
        #pragma unroll
        for (int tt = 0; tt < 8; ++tt) {
            const f16* Ab = &lds[((tt & 1) * 2 + wm) * 8192];
            const f16* Bb = &lds[32768 + ((tt & 1) * 2 + (wn >> 1)) * 8192];
            #pragma unroll
            for (int q = 0; q < 4; ++q) {
                f16x8 af[2][2];
                #pragma unroll
                for (int ml = 0; ml < 2; ++ml) {
                    int rr = (q * 2 + ml) * 16 + l15;
                    #pragma unroll
                    for (int ks = 0; ks < 2; ++ks)
                        af[ml][ks] = *(const f16x8*)&Ab[rr * 64 + (((ks * 4 + g) ^ (rr & 7)) * 8)];
                }
                if (q == 0) {
                    #pragma unroll
                    for (int nf = 0; nf < 4; ++nf) {
                        int rb = (wn & 1) * 64 + nf * 16 + l15;
                        #pragma unroll
                        for (int ks = 0; ks < 2; ++ks)
                            bf[nf][ks] = *(const f16x8*)&Bb[rb * 64 + (((ks * 4 + g) ^ (rb & 7)) * 8)];
                    }
                }
                // staging: q0/q1 -> A(T+1), q2/q3 -> B(T+2)
                if (q <= 1) {
                    bool doA = (tt >= 1 || p > 0) && (tt < 7 || p < 3);
                    if (doA) stageA(p * 8 + tt + 1, q);
                } else {
                    bool doB = (tt < 6 || p < 3);
                    if (doB) stageB(p * 8 + tt + 2, q - 2);
                }
                __builtin_amdgcn_s_barrier();
                __builtin_amdgcn_s_setprio(1);
                #pragma unroll
                for (int ml = 0; ml < 2; ++ml)
                    #pragma unroll
                    for (int nf = 0; nf < 4; ++nf)
                        #pragma unroll
                        for (int ks = 0; ks < 2; ++ks)
                            acc[q * 2 + ml][nf] = __builtin_amdgcn_mfma_f32_16x16x32_f16(
                                af[ml][ks], bf[nf][ks], acc[q * 2 + ml][nf], 0, 0, 0);
                __builtin_amdgcn_s_setprio(0);
                if (q == 3) {
                    if (tt < 6) {
                        asm volatile("s_waitcnt vmcnt(4)" ::: "memory");
                    } else if (tt == 6) {
                        if (p < 3) asm volatile("s_waitcnt vmcnt(4)" ::: "memory");
                        else       asm volatile("s_waitcnt vmcnt(0)" ::: "memory");
                    } else {           // tt == 7
                        if (p < 3) asm volatile("s_waitcnt vmcnt(4)" ::: "memory");
                    }
                }
                __builtin_amdgcn_s_barrier();
            }
        }

        // ---- panel epilogue (wave-local acc; no barrier; overlaps next panel) ----
        int browg = (bmg * 4 + p) * 256 + wm * 128;
        if (bn < 4) {
            #pragma unroll
            for (int mf = 0; mf < 8; ++mf) {
                #pragma unroll
                for (int nf = 0; nf < 4; ++nf) {
                    int col = bn * 256 + wn * 64 + nf * 16 + l15;
                    #pragma unroll
                    for (int j = 0; j < 4; ++j) {
                        int row = browg + mf * 16 + g * 4 + j;
                        float v = acc[mf][nf][j] + biasT[(row & 63) * 1536 + col];
                        qk[(size_t)row * 1024 + col] = (f16)v;
                    }
                }
            }
        } else {
            int bn2 = bn - 4;
            #pragma unroll
            for (int mf = 0; mf < 8; ++mf) {
                int sl = browg + mf * 16 + g * 4;      // global window-row, j=0..3 contiguous
                int win = sl >> 6, s = sl & 63;
                #pragma unroll
                for (int nf = 0; nf < 4; ++nf) {
                    int dl = bn2 * 256 + wn * 64 + nf * 16 + l15;  // 0..511
                    float bo = biasT[1024 + dl];
                    int head = dl >> 6, dd = dl & 63;
                    f16x4 v = {(f16)(acc[mf][nf][0] + bo), (f16)(acc[mf][nf][1] + bo),
                               (f16)(acc[mf][nf][2] + bo), (f16)(acc[mf][nf][3] + bo)};
                    *(f16x4*)(vT + (size_t)win * 32768 + head * 4096 + dd * 64 + s) = v;
                }
            }
        }
        #pragma unroll
        for (int a = 0; a < 8; ++a)
            #pragma unroll
            for (int b = 0; b < 4; ++b) acc[a][b] = zero4;
    }
}

// ---------------- attention: swapped QK^T, in-lane softmax, LDS-staged output ----------------
__global__ __launch_bounds__(512) void attn_k(
        const f16* __restrict__ qk, const f16* __restrict__ vT,
        f16* __restrict__ attn_h) {
    __shared__ __align__(16) char S[64 * 1024];   // 8 heads x 8 KB slices
    int tid = threadIdx.x;
    int lane = tid & 63, h = tid >> 6;   // wave = head
    int l15 = lane & 15, g = lane >> 4;
    const f16* baseqk = qk + (size_t)blockIdx.x * 65536;
    const f16* basev  = vT + (size_t)blockIdx.x * 32768 + h * 4096;
    int qc = h * 64, kc = 512 + h * 64;

    f32x4 zero4 = {0.f, 0.f, 0.f, 0.f};
    f32x4 acc[4][4];
    #pragma unroll
    for (int a = 0; a < 4; ++a)
        #pragma unroll
        for (int b = 0; b < 4; ++b) acc[a][b] = zero4;

    {   // S^T = K @ Q^T : acc[kf][qf], rows=keys, cols=queries
        f16x8 qf[4][2], kf[4][2];
        #pragma unroll
        for (int mf = 0; mf < 4; ++mf)
            #pragma unroll
            for (int ks = 0; ks < 2; ++ks)
                qf[mf][ks] = *reinterpret_cast<const f16x8*>(baseqk + (size_t)(mf * 16 + l15) * 1024 + qc + ks * 32 + g * 8);
        #pragma unroll
        for (int nf = 0; nf < 4; ++nf)
            #pragma unroll
            for (int ks = 0; ks < 2; ++ks)
                kf[nf][ks] = *reinterpret_cast<const f16x8*>(baseqk + (size_t)(nf * 16 + l15) * 1024 + kc + ks * 32 + g * 8);
        #pragma unroll
        for (int ks = 0; ks < 2; ++ks)
            #pragma unroll
            for (int ki = 0; ki < 4; ++ki)
                #pragma unroll
                for (int qi = 0; qi < 4; ++qi)
                    acc[ki][qi] = __builtin_amdgcn_mfma_f32_16x16x32_f16(kf[ki][ks], qf[qi][ks], acc[ki][qi], 0, 0, 0);
    }

    // V fragments: contiguous f16x8 reads (B-frag: lane holds V[s][d=l15])
    f16x8 vf[4][2];
    #pragma unroll
    for (int nf = 0; nf < 4; ++nf)
        #pragma unroll
        for (int ks = 0; ks < 2; ++ks)
            vf[nf][ks] = *reinterpret_cast<const f16x8*>(basev + (nf * 16 + l15) * 64 + ks * 32 + g * 8);

    // softmax per query (col qi*16+l15): 16 keys in-lane + 2 shfl over g; P^T -> LDS [query][key]
    char* Sh = S + h * 8192;
    #pragma unroll
    for (int qi = 0; qi < 4; ++qi) {
        float mx = -1e30f;
        #pragma unroll
        for (int ki = 0; ki < 4; ++ki)
            #pragma unroll
            for (int j = 0; j < 4; ++j) mx = fmaxf(mx, acc[ki][qi][j]);
        mx = fmaxf(mx, __shfl_xor(mx, 16));
        mx = fmaxf(mx, __shfl_xor(mx, 32));
        float sum = 0.f;
        #pragma unroll
        for (int ki = 0; ki < 4; ++ki)
            #pragma unroll
            for (int j = 0; j < 4; ++j) {
                float e = __expf((acc[ki][qi][j] - mx) * 0.125f);
                acc[ki][qi][j] = e;
                sum += e;
            }
        sum += __shfl_xor(sum, 16);
        sum += __shfl_xor(sum, 32);
        float rinv = __fdividef(1.0f, sum);
        int qrow = qi * 16 + l15;
        char* rowp = Sh + qrow * 128;
        int sw = (qrow & 7) << 4;
        #pragma unroll
        for (int ki = 0; ki < 4; ++ki)
            #pragma unroll
            for (int j = 0; j < 4; ++j)
                *(f16*)(rowp + (((ki * 16 + g * 4 + j) * 2) ^ sw)) = (f16)(acc[ki][qi][j] * rinv);
    }

    // out_h = P @ V  (own slice; wave-local)
    f32x4 acc2[4][4];
    #pragma unroll
    for (int a = 0; a < 4; ++a)
        #pragma unroll
        for (int b = 0; b < 4; ++b) acc2[a][b] = zero4;
    #pragma unroll
    for (int ks = 0; ks < 2; ++ks)
        #pragma unroll
        for (int mf = 0; mf < 4; ++mf) {
            int rr = mf * 16 + l15;
            f16x8 pa = *reinterpret_cast<const f16x8*>(Sh + rr * 128 + (((ks * 32 + g * 8) * 2) ^ ((rr & 7) << 4)));
            #pragma unroll
            for (int nf = 0; nf < 4; ++nf)
                acc2[mf][nf] = __builtin_amdgcn_mfma_f32_16x16x32_f16(pa, vf[nf][ks], acc2[mf][nf], 0, 0, 0);
        }

    // stage output into own slice (P dead), then block-cooperative coalesced store
    #pragma unroll
    for (int mf = 0; mf < 4; ++mf)
        #pragma unroll
        for (int nf = 0; nf < 4; ++nf)
            #pragma unroll
            for (int j = 0; j < 4; ++j) {
                int r = mf * 16 + g * 4 + j;
                *(f16*)(Sh + r * 128 + (((nf * 16 + l15) * 2) ^ ((r & 7) << 4))) = (f16)acc2[mf][nf][j];
            }
    __syncthreads();
    f16* dst = attn_h + (size_t)blockIdx.x * 32768;
    #pragma unroll
    for (int i = 0; i < 8; ++i) {
        int c = i * 512 + tid;
        int row = c >> 6, seg = c & 63;
        f16x8 v = *(const f16x8*)(S + (seg >> 3) * 8192 + row * 128 + (((seg & 7) * 16) ^ ((row & 7) << 4)));
        *(f16x8*)(dst + row * 512 + seg * 8) = v;
    }
}

// ---------------- output projection: multi-panel 8-phase GEMM + scatter ----------------
__global__ void __launch_bounds__(512, 2) proj_gemm8_k(
        const f16* __restrict__ attn_h, const f16* __restrict__ Woh,
        const float* __restrict__ b_out, float* __restrict__ out, int nblk, int m0) {
    extern __shared__ f16 lds[];
    int tid = threadIdx.x;
    int lane = tid & 63, wid = tid >> 6;
    int l15 = lane & 15, g = lane >> 4;
    int wm = wid >> 2, wn = wid & 3;
    int sid = (blockIdx.x & 7) * (nblk >> 3) + (blockIdx.x >> 3);
    int bmg = sid >> 1, bn = sid & 1;
    const f16* Ap = attn_h + (size_t)bmg * 4 * 256 * 512;
    const f16* Bp = Woh + (size_t)bn * 256 * 512;

    int li0 = tid, li1 = tid + 512;
    int r0 = li0 >> 3, c0 = li0 & 7, r1 = li1 >> 3, c1 = li1 & 7;
    int off0 = r0 * 512 + ((c0 ^ (r0 & 7)) * 8);
    int off1 = r1 * 512 + ((c1 ^ (r1 & 7)) * 8);

    auto stageA = [&](int Tabs, int h) {
        int dst = ((Tabs & 1) * 2 + h) * 8192 + wid * 512;
        const f16* src = Ap + (size_t)(Tabs >> 3) * 131072 + h * 65536 + (Tabs & 7) * 64;
        gload_lds16(src + off0, (void*)&lds[dst]);
        gload_lds16(src + off1, (void*)&lds[dst + 4096]);
    };
    auto stageB = [&](int Tabs, int h) {
        int dst = 32768 + ((Tabs & 1) * 2 + h) * 8192 + wid * 512;
        const f16* src = Bp + h * 65536 + (Tabs & 7) * 64;
        gload_lds16(src + off0, (void*)&lds[dst]);
        gload_lds16(src + off1, (void*)&lds[dst + 4096]);
    };

    f32x4 acc[8][4];
    f32x4 zero4 = {0.f, 0.f, 0.f, 0.f};
    #pragma unroll
    for (int a = 0; a < 8; ++a)
        #pragma unroll
        for (int b = 0; b < 4; ++b) acc[a][b] = zero4;
    f16x8 bf[4][2];

    stageA(0, 0); stageA(0, 1); stageB(0, 0); stageB(0, 1);
    stageA(1, 0); stageA(1, 1); stageB(1, 0); stageB(1, 1);
    asm volatile("s_waitcnt vmcnt(8)" ::: "memory");
    __builtin_amdgcn_s_barrier();

    for (int p = 0; p < 4; ++p) {
        #pragma unroll
        for (int tt = 0; tt < 8; ++tt) {
            const f16* Ab = &lds[((tt & 1) * 2 + wm) * 8192];
            const f16* Bb = &lds[32768 + ((tt & 1) * 2 + (wn >> 1)) * 8192];
            #pragma unroll
            for (int q = 0; q < 4; ++q) {
                f16x8 af[2][2];
                #pragma unroll
                for (int ml = 0; ml < 2; ++ml) {
                    int rr = (q * 2 + ml) * 16 + l15;
                    #pragma unroll
                    for (int ks = 0; ks < 2; ++ks)
                        af[ml][ks] = *(const f16x8*)&Ab[rr * 64 + (((ks * 4 + g) ^ (rr & 7)) * 8)];
                }
                if (q == 0) {
                    #pragma unroll
                    for (int nf = 0; nf < 4; ++nf) {
                        int rb = (wn & 1) * 64 + nf * 16 + l15;
                        #pragma unroll
                        for (int ks = 0; ks < 2; ++ks)
                            bf[nf][ks] = *(const f16x8*)&Bb[rb * 64 + (((ks * 4 + g) ^ (rb & 7)) * 8)];
                    }
                }
                if (q <= 1) {
                    bool doA = (tt >= 1 || p > 0) && (tt < 7 || p < 3);
                    if (doA) stageA(p * 8 + tt + 1, q);
                } else {
                    bool doB = (tt < 6 || p < 3);
                    if (doB) stageB(p * 8 + tt + 2, q - 2);
                }
                __builtin_amdgcn_s_barrier();
                __builtin_amdgcn_s_setprio(1);
                #pragma unroll
                for (int ml = 0; ml < 2; ++ml)
                    #pragma unroll
                    for (int nf = 0; nf < 4; ++nf)
                        #pragma unroll
                        for (int ks = 0; ks < 2; ++ks)
                            acc[q * 2 + ml][nf] = __builtin_amdgcn_mfma_f32_16x16x32_f16(
                                af[ml][ks], bf[nf][ks], acc[q * 2 + ml][nf], 0, 0, 0);
                __builtin_amdgcn_s_setprio(0);
                if (q == 3) {
                    if (tt < 6) {
                        asm volatile("s_waitcnt vmcnt(4)" ::: "memory");
                    } else if (tt == 6) {
                        if (p < 3) asm volatile("s_waitcnt vmcnt(4)" ::: "memory");
                        else       asm volatile("s_waitcnt vmcnt(0)" ::: "memory");
                    } else {
                        if (p < 3) asm volatile("s_waitcnt vmcnt(4)" ::: "memory");
                    }
                }
                __builtin_amdgcn_s_barrier();
            }
        }

        int browg = (bmg * 4 + p) * 256 + wm * 128;
        int bcolg = bn * 256 + wn * 64;
        #pragma unroll
        for (int nf = 0; nf < 4; ++nf) {
            int col = bcolg + nf * 16 + l15;
            float bo = b_out[col];
            #pragma unroll
            for (int mf = 0; mf < 8; ++mf) {
                #pragma unroll
                for (int j = 0; j < 4; ++j) {
                    int srow = src_row(m0 + browg + mf * 16 + g * 4 + j);
                    out[(size_t)srow * 512 + col] = acc[mf][nf][j] + bo;
                }
            }
        }
        #pragma unroll
        for (int a = 0; a < 8; ++a)
            #pragma unroll
            for (int b = 0; b < 4; ++b) acc[a][b] = zero4;
    }
}

extern "C" void kernel_launch(void* const* d_in, const int* in_sizes, int n_in,
                              void* d_out, int out_size, void* d_ws, size_t ws_size,
                              hipStream_t stream) {
    (void)in_sizes; (void)n_in; (void)out_size;
    const float* x     = (const float*)d_in[0];
    const float* pos   = (const float*)d_in[1];
    const float* W_in  = (const float*)d_in[2];
    const float* b_in  = (const float*)d_in[3];
    const float* W_out = (const float*)d_in[4];
    const float* b_out = (const float*)d_in[5];
    float* out = (float*)d_out;

    char* ws = (char*)d_ws;
    f16*   Wi_h  = (f16*)ws;                  // 1,572,864 B
    f16*   Wo_h  = (f16*)(ws + 1572864);      //   524,288 B
    float* biasT = (float*)(ws + 2097152);    //   393,216 B
    const size_t fixed = 2490368;

    // 4096 B per row: xh/attn_h (1024, aliased) + qk (2048) + vT (1024). chunks=1 proven fit.
    int chunks = 1;
    while (chunks < 64) {
        size_t need = fixed + ((size_t)131072 / chunks) * 4096;
        if (need <= ws_size) break;
        chunks <<= 1;
    }
    int Mc = 131072 / chunks;
    f16* xh = (f16*)(ws + fixed);             // also attn_h (xh dead after qkv_gemm)
    f16* qk = (f16*)(ws + fixed + (size_t)Mc * 1024);
    f16* vT = (f16*)(ws + fixed + (size_t)Mc * 3072);
    int nblk  = (Mc / 1024) * 6;              // 4 panels per block
    int nblk2 = (Mc / 1024) * 2;

    static_cast<void>(hipFuncSetAttribute((const void*)qkv_gemm8_k,
        hipFuncAttributeMaxDynamicSharedMemorySize, 131072));
    static_cast<void>(hipFuncSetAttribute((const void*)proj_gemm8_k,
        hipFuncAttributeMaxDynamicSharedMemorySize, 131072));

    prep_weights_k<<<1024, 256, 0, stream>>>(W_in, W_out, Wi_h, Wo_h);
    prep_bias_k<<<384, 256, 0, stream>>>(pos, W_in, b_in, biasT);
    for (int c = 0; c < chunks; ++c) {
        int m0 = c * Mc;
        prep_x_k<<<Mc / 4, 256, 0, stream>>>(x, xh, m0);
        qkv_gemm8_k<<<nblk, 512, 131072, stream>>>(xh, Wi_h, biasT, qk, vT, nblk);
        attn_k<<<Mc / 64, 512, 0, stream>>>(qk, vT, xh);
        proj_gemm8_k<<<nblk2, 512, 131072, stream>>>(xh, Wo_h, b_out, out, nblk2, m0);
    }
}

// Round 8
// 986.103 us; speedup vs baseline: 1.1371x; 1.1371x over previous
//
#include <hip/hip_runtime.h>

typedef _Float16 f16;
typedef unsigned int u32;
typedef f16 f16x8 __attribute__((ext_vector_type(8)));
typedef f16 f16x4 __attribute__((ext_vector_type(4)));
typedef float f32x4 __attribute__((ext_vector_type(4)));

// N=4,T=8,H=64,W=64,C=512, WS=8, heads=8, head_dim=64
// windows = 2048, tokens/window = 64, M = 131072, K = 512, Nqkv = 1536

__device__ __forceinline__ int src_row(int m) {
    int win = m >> 6, s = m & 63;
    return ((win >> 6) << 12) | (((win >> 3) & 7) << 9) | ((s >> 3) << 6) |
           ((win & 7) << 3) | (s & 7);
}

__device__ __forceinline__ void gload_lds16(const void* g, void* lds) {
    __builtin_amdgcn_global_load_lds(
        (const __attribute__((address_space(1))) u32*)g,
        (__attribute__((address_space(3))) u32*)lds, 16, 0, 0);
}

// ---------------- prep: weights fp32 -> fp16 ----------------
__global__ __launch_bounds__(256) void prep_weights_k(
        const float* __restrict__ Wi, const float* __restrict__ Wo,
        f16* __restrict__ Wi_h, f16* __restrict__ Wo_h) {
    int i = blockIdx.x * 256 + threadIdx.x;    // 262144 float4s total
    const float4* src;
    f16* dst;
    int idx;
    if (i < 196608) { src = (const float4*)Wi; dst = Wi_h; idx = i; }
    else            { src = (const float4*)Wo; dst = Wo_h; idx = i - 196608; }
    float4 v = src[idx];
    f16x4 h = {(f16)v.x, (f16)v.y, (f16)v.z, (f16)v.w};
    *(f16x4*)(dst + (size_t)idx * 4) = h;
}

// ---------------- prep: biasT[s][o] = b_in[o] + (o<1024 ? pos[s]·W_in[o] : 0)
__global__ __launch_bounds__(256) void prep_bias_k(
        const float* __restrict__ pos, const float* __restrict__ Wi,
        const float* __restrict__ b_in, float* __restrict__ biasT) {
    int idx = blockIdx.x * 256 + threadIdx.x;   // 64*1536
    int s = idx / 1536, o = idx % 1536;
    float acc = b_in[o];
    if (o < 1024) {
        const float4* p4 = (const float4*)(pos + (size_t)s * 512);
        const float4* w4 = (const float4*)(Wi + (size_t)o * 512);
        #pragma unroll 4
        for (int c = 0; c < 128; ++c) {
            float4 a = p4[c], b = w4[c];
            acc += a.x * b.x + a.y * b.y + a.z * b.z + a.w * b.w;
        }
    }
    biasT[idx] = acc;
}

// ---------------- prep: x fp32 -> window-major f16 ----------------
__global__ __launch_bounds__(256) void prep_x_k(
        const float* __restrict__ x, f16* __restrict__ xh, int m0) {
    int i = blockIdx.x * 256 + threadIdx.x;    // Mc*64
    int ml = i >> 6, c8 = (i & 63) * 8;
    int sr = src_row(m0 + ml);
    const float4* s4 = (const float4*)(x + (size_t)sr * 512 + c8);
    float4 a = s4[0], b = s4[1];
    f16x8 hv = {(f16)a.x, (f16)a.y, (f16)a.z, (f16)a.w,
                (f16)b.x, (f16)b.y, (f16)b.z, (f16)b.w};
    *(f16x8*)(xh + (size_t)ml * 512 + c8) = hv;
}

// ---------------- QK GEMM: multi-panel 8-phase (4 M-panels/block, 32 tiles, one prologue)
__global__ void __launch_bounds__(512, 2) qk_gemm8_k(
        const f16* __restrict__ xh, const f16* __restrict__ Wh,
        const float* __restrict__ biasT, f16* __restrict__ qk, int nblk) {
    extern __shared__ f16 lds[];
    int tid = threadIdx.x;
    int lane = tid & 63, wid = tid >> 6;
    int l15 = lane & 15, g = lane >> 4;
    int wm = wid >> 2, wn = wid & 3;
    int sid = (blockIdx.x & 7) * (nblk >> 3) + (blockIdx.x >> 3);
    int bmg = sid >> 2, bn = sid & 3;           // bmg: group of 4 M-panels; bn in 0..3
    const f16* Ap = xh + (size_t)bmg * 4 * 256 * 512;
    const f16* Bp = Wh + (size_t)bn * 256 * 512;

    int li0 = tid, li1 = tid + 512;
    int r0 = li0 >> 3, c0 = li0 & 7, r1 = li1 >> 3, c1 = li1 & 7;
    int off0 = r0 * 512 + ((c0 ^ (r0 & 7)) * 8);
    int off1 = r1 * 512 + ((c1 ^ (r1 & 7)) * 8);

    auto stageA = [&](int Tabs, int h) {
        int dst = ((Tabs & 1) * 2 + h) * 8192 + wid * 512;
        const f16* src = Ap + (size_t)(Tabs >> 3) * 131072 + h * 65536 + (Tabs & 7) * 64;
        gload_lds16(src + off0, (void*)&lds[dst]);
        gload_lds16(src + off1, (void*)&lds[dst + 4096]);
    };
    auto stageB = [&](int Tabs, int h) {
        int dst = 32768 + ((Tabs & 1) * 2 + h) * 8192 + wid * 512;
        const f16* src = Bp + h * 65536 + (Tabs & 7) * 64;
        gload_lds16(src + off0, (void*)&lds[dst]);
        gload_lds16(src + off1, (void*)&lds[dst + 4096]);
    };

    f32x4 acc[8][4];
    f32x4 zero4 = {0.f, 0.f, 0.f, 0.f};
    #pragma unroll
    for (int a = 0; a < 8; ++a)
        #pragma unroll
        for (int b = 0; b < 4; ++b) acc[a][b] = zero4;
    f16x8 bf[4][2];

    stageA(0, 0); stageA(0, 1); stageB(0, 0); stageB(0, 1);
    stageA(1, 0); stageA(1, 1); stageB(1, 0); stageB(1, 1);
    asm volatile("s_waitcnt vmcnt(8)" ::: "memory");
    __builtin_amdgcn_s_barrier();

    for (int p = 0; p < 4; ++p) {
        #pragma unroll
        for (int tt = 0; tt < 8; ++tt) {
            const f16* Ab = &lds[((tt & 1) * 2 + wm) * 8192];
            const f16* Bb = &lds[32768 + ((tt & 1) * 2 + (wn >> 1)) * 8192];
            #pragma unroll
            for (int q = 0; q < 4; ++q) {
                f16x8 af[2][2];
                #pragma unroll
                for (int ml = 0; ml < 2; ++ml) {
                    int rr = (q * 2 + ml) * 16 + l15;
                    #pragma unroll
                    for (int ks = 0; ks < 2; ++ks)
                        af[ml][ks] = *(const f16x8*)&Ab[rr * 64 + (((ks * 4 + g) ^ (rr & 7)) * 8)];
                }
                if (q == 0) {
                    #pragma unroll
                    for (int nf = 0; nf < 4; ++nf) {
                        int rb = (wn & 1) * 64 + nf * 16 + l15;
                        #pragma unroll
                        for (int ks = 0; ks < 2; ++ks)
                            bf[nf][ks] = *(const f16x8*)&Bb[rb * 64 + (((ks * 4 + g) ^ (rb & 7)) * 8)];
                    }
                }
                if (q <= 1) {
                    bool doA = (tt >= 1 || p > 0) && (tt < 7 || p < 3);
                    if (doA) stageA(p * 8 + tt + 1, q);
                } else {
                    bool doB = (tt < 6 || p < 3);
                    if (doB) stageB(p * 8 + tt + 2, q - 2);
                }
                __builtin_amdgcn_s_barrier();
                __builtin_amdgcn_s_setprio(1);
                #pragma unroll
                for (int ml = 0; ml < 2; ++ml)
                    #pragma unroll
                    for (int nf = 0; nf < 4; ++nf)
                        #pragma unroll
                        for (int ks = 0; ks < 2; ++ks)
                            acc[q * 2 + ml][nf] = __builtin_amdgcn_mfma_f32_16x16x32_f16(
                                af[ml][ks], bf[nf][ks], acc[q * 2 + ml][nf], 0, 0, 0);
                __builtin_amdgcn_s_setprio(0);
                if (q == 3) {
                    if (tt < 6) {
                        asm volatile("s_waitcnt vmcnt(4)" ::: "memory");
                    } else if (tt == 6) {
                        if (p < 3) asm volatile("s_waitcnt vmcnt(4)" ::: "memory");
                        else       asm volatile("s_waitcnt vmcnt(0)" ::: "memory");
                    } else {
                        if (p < 3) asm volatile("s_waitcnt vmcnt(4)" ::: "memory");
                    }
                }
                __builtin_amdgcn_s_barrier();
            }
        }
        // panel epilogue (proven 32B-chunk granularity; overlaps next panel)
        int browg = (bmg * 4 + p) * 256 + wm * 128;
        #pragma unroll
        for (int mf = 0; mf < 8; ++mf) {
            #pragma unroll
            for (int nf = 0; nf < 4; ++nf) {
                int col = bn * 256 + wn * 64 + nf * 16 + l15;
                #pragma unroll
                for (int j = 0; j < 4; ++j) {
                    int row = browg + mf * 16 + g * 4 + j;
                    float v = acc[mf][nf][j] + biasT[(row & 63) * 1536 + col];
                    qk[(size_t)row * 1024 + col] = (f16)v;
                }
            }
        }
        #pragma unroll
        for (int a = 0; a < 8; ++a)
            #pragma unroll
            for (int b = 0; b < 4; ++b) acc[a][b] = zero4;
    }
}

// ---------------- V GEMM (swapped operands): vT[d][s] = Wv[d]·xh[s] + b
// M=512 (d), N=131072 (s); multi-panel over 4 s-panels/block; epilogue 32B-contiguous along s.
__global__ void __launch_bounds__(512, 2) v_gemm8_k(
        const f16* __restrict__ xh, const f16* __restrict__ Wh,
        const float* __restrict__ biasT, f16* __restrict__ vT, int nblk) {
    extern __shared__ f16 lds[];
    int tid = threadIdx.x;
    int lane = tid & 63, wid = tid >> 6;
    int l15 = lane & 15, g = lane >> 4;
    int wm = wid >> 2, wn = wid & 3;
    int sid = (blockIdx.x & 7) * (nblk >> 3) + (blockIdx.x >> 3);
    int bng = sid >> 1, bm = sid & 1;           // bng: group of 4 s-panels; bm in 0..1 (d)
    const f16* Apw = Wh + (size_t)(1024 + bm * 256) * 512;   // Wv rows
    const f16* Bp  = xh + (size_t)bng * 4 * 256 * 512;       // s-panels

    int li0 = tid, li1 = tid + 512;
    int r0 = li0 >> 3, c0 = li0 & 7, r1 = li1 >> 3, c1 = li1 & 7;
    int off0 = r0 * 512 + ((c0 ^ (r0 & 7)) * 8);
    int off1 = r1 * 512 + ((c1 ^ (r1 & 7)) * 8);

    auto stageA = [&](int Tabs, int h) {        // Wv tile: depends on K-pos only
        int dst = ((Tabs & 1) * 2 + h) * 8192 + wid * 512;
        const f16* src = Apw + h * 65536 + (Tabs & 7) * 64;
        gload_lds16(src + off0, (void*)&lds[dst]);
        gload_lds16(src + off1, (void*)&lds[dst + 4096]);
    };
    auto stageB = [&](int Tabs, int h) {        // xh tile: panel advances
        int dst = 32768 + ((Tabs & 1) * 2 + h) * 8192 + wid * 512;
        const f16* src = Bp + (size_t)(Tabs >> 3) * 131072 + h * 65536 + (Tabs & 7) * 64;
        gload_lds16(src + off0, (void*)&lds[dst]);
        gload_lds16(src + off1, (void*)&lds[dst + 4096]);
    };

    f32x4 acc[8][4];
    f32x4 zero4 = {0.f, 0.f, 0.f, 0.f};
    #pragma unroll
    for (int a = 0; a < 8; ++a)
        #pragma unroll
        for (int b = 0; b < 4; ++b) acc[a][b] = zero4;
    f16x8 bf[4][2];

    stageA(0, 0); stageA(0, 1); stageB(0, 0); stageB(0, 1);
    stageA(1, 0); stageA(1, 1); stageB(1, 0); stageB(1, 1);
    asm volatile("s_waitcnt vmcnt(8)" ::: "memory");
    __builtin_amdgcn_s_barrier();

    for (int p = 0; p < 4; ++p) {
        #pragma unroll
        for (int tt = 0; tt < 8; ++tt) {
            const f16* Ab = &lds[((tt & 1) * 2 + wm) * 8192];
            const f16* Bb = &lds[32768 + ((tt & 1) * 2 + (wn >> 1)) * 8192];
            #pragma unroll
            for (int q = 0; q < 4; ++q) {
                f16x8 af[2][2];
                #pragma unroll
                for (int ml = 0; ml < 2; ++ml) {
                    int rr = (q * 2 + ml) * 16 + l15;
                    #pragma unroll
                    for (int ks = 0; ks < 2; ++ks)
                        af[ml][ks] = *(const f16x8*)&Ab[rr * 64 + (((ks * 4 + g) ^ (rr & 7)) * 8)];
                }
                if (q == 0) {
                    #pragma unroll
                    for (int nf = 0; nf < 4; ++nf) {
                        int rb = (wn & 1) * 64 + nf * 16 + l15;
                        #pragma unroll
                        for (int ks = 0; ks < 2; ++ks)
                            bf[nf][ks] = *(const f16x8*)&Bb[rb * 64 + (((ks * 4 + g) ^ (rb & 7)) * 8)];
                    }
                }
                if (q <= 1) {
                    bool doA = (tt >= 1 || p > 0) && (tt < 7 || p < 3);
                    if (doA) stageA(p * 8 + tt + 1, q);
                } else {
                    bool doB = (tt < 6 || p < 3);
                    if (doB) stageB(p * 8 + tt + 2, q - 2);
                }
                __builtin_amdgcn_s_barrier();
                __builtin_amdgcn_s_setprio(1);
                #pragma unroll
                for (int ml = 0; ml < 2; ++ml)
                    #pragma unroll
                    for (int nf = 0; nf < 4; ++nf)
                        #pragma unroll
                        for (int ks = 0; ks < 2; ++ks)
                            acc[q * 2 + ml][nf] = __builtin_amdgcn_mfma_f32_16x16x32_f16(
                                af[ml][ks], bf[nf][ks], acc[q * 2 + ml][nf], 0, 0, 0);
                __builtin_amdgcn_s_setprio(0);
                if (q == 3) {
                    if (tt < 6) {
                        asm volatile("s_waitcnt vmcnt(4)" ::: "memory");
                    } else if (tt == 6) {
                        if (p < 3) asm volatile("s_waitcnt vmcnt(4)" ::: "memory");
                        else       asm volatile("s_waitcnt vmcnt(0)" ::: "memory");
                    } else {
                        if (p < 3) asm volatile("s_waitcnt vmcnt(4)" ::: "memory");
                    }
                }
                __builtin_amdgcn_s_barrier();
            }
        }
        // epilogue: rows = d, cols = s (16 lanes x 2B = 32B contiguous along s)
        int wing = (bng * 4 + p) * 4 + wn;       // window index
        #pragma unroll
        for (int mf = 0; mf < 8; ++mf) {
            int dP = bm * 256 + wm * 128 + mf * 16 + g * 4;
            float bo[4];
            #pragma unroll
            for (int j = 0; j < 4; ++j) bo[j] = biasT[1024 + dP + j];
            #pragma unroll
            for (int nf = 0; nf < 4; ++nf) {
                int s6 = nf * 16 + l15;
                #pragma unroll
                for (int j = 0; j < 4; ++j) {
                    int d = dP + j;
                    vT[(size_t)wing * 32768 + (d >> 6) * 4096 + (d & 63) * 64 + s6] =
                        (f16)(acc[mf][nf][j] + bo[j]);
                }
            }
        }
        #pragma unroll
        for (int a = 0; a < 8; ++a)
            #pragma unroll
            for (int b = 0; b < 4; ++b) acc[a][b] = zero4;
    }
}

// ---------------- attention: swapped QK^T, in-lane softmax, LDS-staged output ----------------
__global__ __launch_bounds__(512) void attn_k(
        const f16* __restrict__ qk, const f16* __restrict__ vT,
        f16* __restrict__ attn_h) {
    __shared__ __align__(16) char S[64 * 1024];   // 8 heads x 8 KB slices
    int tid = threadIdx.x;
    int lane = tid & 63, h = tid >> 6;   // wave = head
    int l15 = lane & 15, g = lane >> 4;
    const f16* baseqk = qk + (size_t)blockIdx.x * 65536;
    const f16* basev  = vT + (size_t)blockIdx.x * 32768 + h * 4096;
    int qc = h * 64, kc = 512 + h * 64;

    f32x4 zero4 = {0.f, 0.f, 0.f, 0.f};
    f32x4 acc[4][4];
    #pragma unroll
    for (int a = 0; a < 4; ++a)
        #pragma unroll
        for (int b = 0; b < 4; ++b) acc[a][b] = zero4;

    {   // S^T = K @ Q^T : acc[kf][qf]
        f16x8 qf[4][2], kf[4][2];
        #pragma unroll
        for (int mf = 0; mf < 4; ++mf)
            #pragma unroll
            for (int ks = 0; ks < 2; ++ks)
                qf[mf][ks] = *reinterpret_cast<const f16x8*>(baseqk + (size_t)(mf * 16 + l15) * 1024 + qc + ks * 32 + g * 8);
        #pragma unroll
        for (int nf = 0; nf < 4; ++nf)
            #pragma unroll
            for (int ks = 0; ks < 2; ++ks)
                kf[nf][ks] = *reinterpret_cast<const f16x8*>(baseqk + (size_t)(nf * 16 + l15) * 1024 + kc + ks * 32 + g * 8);
        #pragma unroll
        for (int ks = 0; ks < 2; ++ks)
            #pragma unroll
            for (int ki = 0; ki < 4; ++ki)
                #pragma unroll
                for (int qi = 0; qi < 4; ++qi)
                    acc[ki][qi] = __builtin_amdgcn_mfma_f32_16x16x32_f16(kf[ki][ks], qf[qi][ks], acc[ki][qi], 0, 0, 0);
    }

    // V fragments: contiguous f16x8 reads
    f16x8 vf[4][2];
    #pragma unroll
    for (int nf = 0; nf < 4; ++nf)
        #pragma unroll
        for (int ks = 0; ks < 2; ++ks)
            vf[nf][ks] = *reinterpret_cast<const f16x8*>(basev + (nf * 16 + l15) * 64 + ks * 32 + g * 8);

    // softmax per query: 16 keys in-lane + 2 shfl; P^T -> LDS [query][key]
    char* Sh = S + h * 8192;
    #pragma unroll
    for (int qi = 0; qi < 4; ++qi) {
        float mx = -1e30f;
        #pragma unroll
        for (int ki = 0; ki < 4; ++ki)
            #pragma unroll
            for (int j = 0; j < 4; ++j) mx = fmaxf(mx, acc[ki][qi][j]);
        mx = fmaxf(mx, __shfl_xor(mx, 16));
        mx = fmaxf(mx, __shfl_xor(mx, 32));
        float sum = 0.f;
        #pragma unroll
        for (int ki = 0; ki < 4; ++ki)
            #pragma unroll
            for (int j = 0; j < 4; ++j) {
                float e = __expf((acc[ki][qi][j] - mx) * 0.125f);
                acc[ki][qi][j] = e;
                sum += e;
            }
        sum += __shfl_xor(sum, 16);
        sum += __shfl_xor(sum, 32);
        float rinv = __fdividef(1.0f, sum);
        int qrow = qi * 16 + l15;
        char* rowp = Sh + qrow * 128;
        int sw = (qrow & 7) << 4;
        #pragma unroll
        for (int ki = 0; ki < 4; ++ki)
            #pragma unroll
            for (int j = 0; j < 4; ++j)
                *(f16*)(rowp + (((ki * 16 + g * 4 + j) * 2) ^ sw)) = (f16)(acc[ki][qi][j] * rinv);
    }

    // out_h = P @ V
    f32x4 acc2[4][4];
    #pragma unroll
    for (int a = 0; a < 4; ++a)
        #pragma unroll
        for (int b = 0; b < 4; ++b) acc2[a][b] = zero4;
    #pragma unroll
    for (int ks = 0; ks < 2; ++ks)
        #pragma unroll
        for (int mf = 0; mf < 4; ++mf) {
            int rr = mf * 16 + l15;
            f16x8 pa = *reinterpret_cast<const f16x8*>(Sh + rr * 128 + (((ks * 32 + g * 8) * 2) ^ ((rr & 7) << 4)));
            #pragma unroll
            for (int nf = 0; nf < 4; ++nf)
                acc2[mf][nf] = __builtin_amdgcn_mfma_f32_16x16x32_f16(pa, vf[nf][ks], acc2[mf][nf], 0, 0, 0);
        }

    // stage output, then block-cooperative coalesced store
    #pragma unroll
    for (int mf = 0; mf < 4; ++mf)
        #pragma unroll
        for (int nf = 0; nf < 4; ++nf)
            #pragma unroll
            for (int j = 0; j < 4; ++j) {
                int r = mf * 16 + g * 4 + j;
                *(f16*)(Sh + r * 128 + (((nf * 16 + l15) * 2) ^ ((r & 7) << 4))) = (f16)acc2[mf][nf][j];
            }
    __syncthreads();
    f16* dst = attn_h + (size_t)blockIdx.x * 32768;
    #pragma unroll
    for (int i = 0; i < 8; ++i) {
        int c = i * 512 + tid;
        int row = c >> 6, seg = c & 63;
        f16x8 v = *(const f16x8*)(S + (seg >> 3) * 8192 + row * 128 + (((seg & 7) * 16) ^ ((row & 7) << 4)));
        *(f16x8*)(dst + row * 512 + seg * 8) = v;
    }
}

// ---------------- output projection: single-panel 8-phase GEMM + scatter (R6) ----------------
__global__ void __launch_bounds__(512, 2) proj_gemm8_k(
        const f16* __restrict__ attn_h, const f16* __restrict__ Woh,
        const float* __restrict__ b_out, float* __restrict__ out, int nblk, int m0) {
    extern __shared__ f16 lds[];
    int tid = threadIdx.x;
    int lane = tid & 63, wid = tid >> 6;
    int l15 = lane & 15, g = lane >> 4;
    int wm = wid >> 2, wn = wid & 3;
    int sid = (blockIdx.x & 7) * (nblk >> 3) + (blockIdx.x >> 3);
    int bm = sid >> 1, bn = sid & 1;
    const f16* Ap = attn_h + (size_t)bm * 256 * 512;
    const f16* Bp = Woh + (size_t)bn * 256 * 512;

    int li0 = tid, li1 = tid + 512;
    int r0 = li0 >> 3, c0 = li0 & 7, r1 = li1 >> 3, c1 = li1 & 7;
    int off0 = r0 * 512 + ((c0 ^ (r0 & 7)) * 8);
    int off1 = r1 * 512 + ((c1 ^ (r1 & 7)) * 8);

    auto stage = [&](const f16* panel, int ldsbase, int tt, int h) {
        int tb = tt & 1;
        int dst = ldsbase + (tb * 2 + h) * 8192 + wid * 512;
        const f16* src = panel + h * 65536 + tt * 64;
        gload_lds16(src + off0, (void*)&lds[dst]);
        gload_lds16(src + off1, (void*)&lds[dst + 4096]);
    };

    f32x4 acc[8][4];
    f32x4 zero4 = {0.f, 0.f, 0.f, 0.f};
    #pragma unroll
    for (int a = 0; a < 8; ++a)
        #pragma unroll
        for (int b = 0; b < 4; ++b) acc[a][b] = zero4;
    f16x8 bf[4][2];

    stage(Ap, 0, 0, 0); stage(Ap, 0, 0, 1);
    stage(Bp, 32768, 0, 0); stage(Bp, 32768, 0, 1);
    stage(Ap, 0, 1, 0); stage(Ap, 0, 1, 1);
    stage(Bp, 32768, 1, 0); stage(Bp, 32768, 1, 1);
    asm volatile("s_waitcnt vmcnt(8)" ::: "memory");
    __builtin_amdgcn_s_barrier();

    #pragma unroll
    for (int tt = 0; tt < 8; ++tt) {
        int tb = tt & 1;
        const f16* Ab = &lds[(tb * 2 + wm) * 8192];
        const f16* Bb = &lds[32768 + (tb * 2 + (wn >> 1)) * 8192];
        #pragma unroll
        for (int q = 0; q < 4; ++q) {
            f16x8 af[2][2];
            #pragma unroll
            for (int ml = 0; ml < 2; ++ml) {
                int rr = (q * 2 + ml) * 16 + l15;
                #pragma unroll
                for (int ks = 0; ks < 2; ++ks)
                    af[ml][ks] = *(const f16x8*)&Ab[rr * 64 + (((ks * 4 + g) ^ (rr & 7)) * 8)];
            }
            if (q == 0) {
                #pragma unroll
                for (int nf = 0; nf < 4; ++nf) {
                    int rb = (wn & 1) * 64 + nf * 16 + l15;
                    #pragma unroll
                    for (int ks = 0; ks < 2; ++ks)
                        bf[nf][ks] = *(const f16x8*)&Bb[rb * 64 + (((ks * 4 + g) ^ (rb & 7)) * 8)];
                }
            }
            if (q <= 1) {
                if ((tt & 1) ? (tt + 1 < 8) : (tt >= 2)) stage(Ap, 0, tt + 1, q);
            } else {
                if (tt + 2 < 8) stage(Bp, 32768, tt + 2, q - 2);
            }
            __builtin_amdgcn_s_barrier();
            __builtin_amdgcn_s_setprio(1);
            #pragma unroll
            for (int ml = 0; ml < 2; ++ml)
                #pragma unroll
                for (int nf = 0; nf < 4; ++nf)
                    #pragma unroll
                    for (int ks = 0; ks < 2; ++ks)
                        acc[q * 2 + ml][nf] = __builtin_amdgcn_mfma_f32_16x16x32_f16(
                            af[ml][ks], bf[nf][ks], acc[q * 2 + ml][nf], 0, 0, 0);
            __builtin_amdgcn_s_setprio(0);
            if (q == 3) {
                if (tt < 6)       asm volatile("s_waitcnt vmcnt(4)" ::: "memory");
                else if (tt == 6) asm volatile("s_waitcnt vmcnt(0)" ::: "memory");
            }
            __builtin_amdgcn_s_barrier();
        }
    }

    int browg = bm * 256 + wm * 128, bcolg = bn * 256 + wn * 64;
    #pragma unroll
    for (int nf = 0; nf < 4; ++nf) {
        int col = bcolg + nf * 16 + l15;
        float bo = b_out[col];
        #pragma unroll
        for (int mf = 0; mf < 8; ++mf) {
            #pragma unroll
            for (int j = 0; j < 4; ++j) {
                int srow = src_row(m0 + browg + mf * 16 + g * 4 + j);
                out[(size_t)srow * 512 + col] = acc[mf][nf][j] + bo;
            }
        }
    }
}

extern "C" void kernel_launch(void* const* d_in, const int* in_sizes, int n_in,
                              void* d_out, int out_size, void* d_ws, size_t ws_size,
                              hipStream_t stream) {
    (void)in_sizes; (void)n_in; (void)out_size;
    const float* x     = (const float*)d_in[0];
    const float* pos   = (const float*)d_in[1];
    const float* W_in  = (const float*)d_in[2];
    const float* b_in  = (const float*)d_in[3];
    const float* W_out = (const float*)d_in[4];
    const float* b_out = (const float*)d_in[5];
    float* out = (float*)d_out;

    char* ws = (char*)d_ws;
    f16*   Wi_h  = (f16*)ws;                  // 1,572,864 B
    f16*   Wo_h  = (f16*)(ws + 1572864);      //   524,288 B
    float* biasT = (float*)(ws + 2097152);    //   393,216 B
    const size_t fixed = 2490368;

    // 4096 B per row: xh/attn_h (1024, aliased) + qk (2048) + vT (1024). chunks=1 proven fit.
    int chunks = 1;
    while (chunks < 64) {
        size_t need = fixed + ((size_t)131072 / chunks) * 4096;
        if (need <= ws_size) break;
        chunks <<= 1;
    }
    int Mc = 131072 / chunks;
    f16* xh = (f16*)(ws + fixed);             // also attn_h (xh dead after v_gemm)
    f16* qk = (f16*)(ws + fixed + (size_t)Mc * 1024);
    f16* vT = (f16*)(ws + fixed + (size_t)Mc * 3072);
    int nblkQ = (Mc / 1024) * 4;              // 512 at chunks=1
    int nblkV = (Mc / 1024) * 2;              // 256
    int nblkP = (Mc / 256) * 2;               // 1024

    static_cast<void>(hipFuncSetAttribute((const void*)qk_gemm8_k,
        hipFuncAttributeMaxDynamicSharedMemorySize, 131072));
    static_cast<void>(hipFuncSetAttribute((const void*)v_gemm8_k,
        hipFuncAttributeMaxDynamicSharedMemorySize, 131072));
    static_cast<void>(hipFuncSetAttribute((const void*)proj_gemm8_k,
        hipFuncAttributeMaxDynamicSharedMemorySize, 131072));

    prep_weights_k<<<1024, 256, 0, stream>>>(W_in, W_out, Wi_h, Wo_h);
    prep_bias_k<<<384, 256, 0, stream>>>(pos, W_in, b_in, biasT);
    for (int c = 0; c < chunks; ++c) {
        int m0 = c * Mc;
        prep_x_k<<<Mc / 4, 256, 0, stream>>>(x, xh, m0);
        qk_gemm8_k<<<nblkQ, 512, 131072, stream>>>(xh, Wi_h, biasT, qk, nblkQ);
        v_gemm8_k<<<nblkV, 512, 131072, stream>>>(xh, Wi_h, biasT, vT, nblkV);
        attn_k<<<Mc / 64, 512, 0, stream>>>(qk, vT, xh);
        proj_gemm8_k<<<nblkP, 512, 131072, stream>>>(xh, Wo_h, b_out, out, nblkP, m0);
    }
}

// Round 9
// 798.725 us; speedup vs baseline: 1.4039x; 1.2346x over previous
//
#include <hip/hip_runtime.h>

typedef _Float16 f16;
typedef unsigned int u32;
typedef f16 f16x8 __attribute__((ext_vector_type(8)));
typedef f16 f16x4 __attribute__((ext_vector_type(4)));
typedef float f32x4 __attribute__((ext_vector_type(4)));

// N=4,T=8,H=64,W=64,C=512, WS=8, heads=8, head_dim=64
// windows = 2048, tokens/window = 64, M = 131072, K = 512, Nqkv = 1536

__device__ __forceinline__ int src_row(int m) {
    int win = m >> 6, s = m & 63;
    return ((win >> 6) << 12) | (((win >> 3) & 7) << 9) | ((s >> 3) << 6) |
           ((win & 7) << 3) | (s & 7);
}

__device__ __forceinline__ void gload_lds16(const void* g, void* lds) {
    __builtin_amdgcn_global_load_lds(
        (const __attribute__((address_space(1))) u32*)g,
        (__attribute__((address_space(3))) u32*)lds, 16, 0, 0);
}

// ---------------- prep: weights fp32 -> fp16 ----------------
__global__ __launch_bounds__(256) void prep_weights_k(
        const float* __restrict__ Wi, const float* __restrict__ Wo,
        f16* __restrict__ Wi_h, f16* __restrict__ Wo_h) {
    int i = blockIdx.x * 256 + threadIdx.x;    // 262144 float4s total
    const float4* src;
    f16* dst;
    int idx;
    if (i < 196608) { src = (const float4*)Wi; dst = Wi_h; idx = i; }
    else            { src = (const float4*)Wo; dst = Wo_h; idx = i - 196608; }
    float4 v = src[idx];
    f16x4 h = {(f16)v.x, (f16)v.y, (f16)v.z, (f16)v.w};
    *(f16x4*)(dst + (size_t)idx * 4) = h;
}

// ---------------- prep: biasT[s][o] = b_in[o] + (o<1024 ? pos[s]·W_in[o] : 0)
__global__ __launch_bounds__(256) void prep_bias_k(
        const float* __restrict__ pos, const float* __restrict__ Wi,
        const float* __restrict__ b_in, float* __restrict__ biasT) {
    int idx = blockIdx.x * 256 + threadIdx.x;   // 64*1536
    int s = idx / 1536, o = idx % 1536;
    float acc = b_in[o];
    if (o < 1024) {
        const float4* p4 = (const float4*)(pos + (size_t)s * 512);
        const float4* w4 = (const float4*)(Wi + (size_t)o * 512);
        #pragma unroll 4
        for (int c = 0; c < 128; ++c) {
            float4 a = p4[c], b = w4[c];
            acc += a.x * b.x + a.y * b.y + a.z * b.z + a.w * b.w;
        }
    }
    biasT[idx] = acc;
}

// ---------------- prep: x fp32 -> window-major f16 ----------------
__global__ __launch_bounds__(256) void prep_x_k(
        const float* __restrict__ x, f16* __restrict__ xh, int m0) {
    int i = blockIdx.x * 256 + threadIdx.x;    // Mc*64
    int ml = i >> 6, c8 = (i & 63) * 8;
    int sr = src_row(m0 + ml);
    const float4* s4 = (const float4*)(x + (size_t)sr * 512 + c8);
    float4 a = s4[0], b = s4[1];
    f16x8 hv = {(f16)a.x, (f16)a.y, (f16)a.z, (f16)a.w,
                (f16)b.x, (f16)b.y, (f16)b.z, (f16)b.w};
    *(f16x8*)(xh + (size_t)ml * 512 + c8) = hv;
}

// ---------------- QKV GEMM: 256x256 tile, BK=64, 8-phase counted-vmcnt (R5, single-panel)
// Q,K cols (bn<4) -> qk[row][0..1023]; V cols (bn>=4) -> vT[win][head][d][s] via LDS transpose
__global__ void __launch_bounds__(512, 2) qkv_gemm8_k(
        const f16* __restrict__ xh, const f16* __restrict__ Wh,
        const float* __restrict__ biasT, f16* __restrict__ qk,
        f16* __restrict__ vT, int nblk) {
    extern __shared__ f16 lds[];
    int tid = threadIdx.x;
    int lane = tid & 63, wid = tid >> 6;
    int l15 = lane & 15, g = lane >> 4;
    int wm = wid >> 2, wn = wid & 3;            // 2M x 4N waves, wave tile 128x64
    int sid = (blockIdx.x & 7) * (nblk >> 3) + (blockIdx.x >> 3);
    int bm = sid / 6, bn = sid % 6;
    const f16* Ap = xh + (size_t)bm * 256 * 512;
    const f16* Bp = Wh + (size_t)bn * 256 * 512;

    int li0 = tid, li1 = tid + 512;
    int r0 = li0 >> 3, c0 = li0 & 7, r1 = li1 >> 3, c1 = li1 & 7;
    int off0 = r0 * 512 + ((c0 ^ (r0 & 7)) * 8);
    int off1 = r1 * 512 + ((c1 ^ (r1 & 7)) * 8);

    auto stage = [&](const f16* panel, int ldsbase, int tt, int h) {
        int tb = tt & 1;
        int dst = ldsbase + (tb * 2 + h) * 8192 + wid * 512;   // wave-uniform
        const f16* src = panel + h * 65536 + tt * 64;
        gload_lds16(src + off0, (void*)&lds[dst]);
        gload_lds16(src + off1, (void*)&lds[dst + 4096]);
    };

    f32x4 acc[8][4];
    f32x4 zero4 = {0.f, 0.f, 0.f, 0.f};
    #pragma unroll
    for (int a = 0; a < 8; ++a)
        #pragma unroll
        for (int b = 0; b < 4; ++b) acc[a][b] = zero4;
    f16x8 bf[4][2];

    stage(Ap, 0, 0, 0); stage(Ap, 0, 0, 1);
    stage(Bp, 32768, 0, 0); stage(Bp, 32768, 0, 1);
    stage(Ap, 0, 1, 0); stage(Ap, 0, 1, 1);
    stage(Bp, 32768, 1, 0); stage(Bp, 32768, 1, 1);
    asm volatile("s_waitcnt vmcnt(8)" ::: "memory");   // tile0 landed; tile1 in flight
    __builtin_amdgcn_s_barrier();

    #pragma unroll
    for (int tt = 0; tt < 8; ++tt) {
        int tb = tt & 1;
        const f16* Ab = &lds[(tb * 2 + wm) * 8192];
        const f16* Bb = &lds[32768 + (tb * 2 + (wn >> 1)) * 8192];
        #pragma unroll
        for (int q = 0; q < 4; ++q) {
            f16x8 af[2][2];
            #pragma unroll
            for (int ml = 0; ml < 2; ++ml) {
                int rr = (q * 2 + ml) * 16 + l15;
                #pragma unroll
                for (int ks = 0; ks < 2; ++ks)
                    af[ml][ks] = *(const f16x8*)&Ab[rr * 64 + (((ks * 4 + g) ^ (rr & 7)) * 8)];
            }
            if (q == 0) {
                #pragma unroll
                for (int nf = 0; nf < 4; ++nf) {
                    int rb = (wn & 1) * 64 + nf * 16 + l15;
                    #pragma unroll
                    for (int ks = 0; ks < 2; ++ks)
                        bf[nf][ks] = *(const f16x8*)&Bb[rb * 64 + (((ks * 4 + g) ^ (rb & 7)) * 8)];
                }
            }
            if (q <= 1) {
                if ((tt & 1) ? (tt + 1 < 8) : (tt >= 2)) stage(Ap, 0, tt + 1, q);
            } else {
                if (tt + 2 < 8) stage(Bp, 32768, tt + 2, q - 2);
            }
            __builtin_amdgcn_s_barrier();
            __builtin_amdgcn_s_setprio(1);
            #pragma unroll
            for (int ml = 0; ml < 2; ++ml)
                #pragma unroll
                for (int nf = 0; nf < 4; ++nf)
                    #pragma unroll
                    for (int ks = 0; ks < 2; ++ks)
                        acc[q * 2 + ml][nf] = __builtin_amdgcn_mfma_f32_16x16x32_f16(
                            af[ml][ks], bf[nf][ks], acc[q * 2 + ml][nf], 0, 0, 0);
            __builtin_amdgcn_s_setprio(0);
            if (q == 3) {
                if (tt < 6)       asm volatile("s_waitcnt vmcnt(4)" ::: "memory");
                else if (tt == 6) asm volatile("s_waitcnt vmcnt(0)" ::: "memory");
            }
            __builtin_amdgcn_s_barrier();
        }
    }

    int browg = bm * 256 + wm * 128;
    if (bn < 4) {
        // Q,K: bias (row-dependent) + f16 store, row stride 1024 (proven granularity)
        #pragma unroll
        for (int mf = 0; mf < 8; ++mf) {
            #pragma unroll
            for (int nf = 0; nf < 4; ++nf) {
                int col = bn * 256 + wn * 64 + nf * 16 + l15;
                #pragma unroll
                for (int j = 0; j < 4; ++j) {
                    int row = browg + mf * 16 + g * 4 + j;
                    float v = acc[mf][nf][j] + biasT[(row & 63) * 1536 + col];
                    qk[(size_t)row * 1024 + col] = (f16)v;
                }
            }
        }
    } else {
        // V: bias is row-independent. Transpose via LDS -> vT[win][head][d][s]
        __syncthreads();
        char* T = (char*)lds;   // 256 d-rows x 512 B, XOR-swizzled
        int bn2 = bn - 4;
        #pragma unroll
        for (int mf = 0; mf < 8; ++mf) {
            #pragma unroll
            for (int nf = 0; nf < 4; ++nf) {
                int dl = wn * 64 + nf * 16 + l15;           // 0..255
                float bo = biasT[1024 + bn2 * 256 + dl];
                #pragma unroll
                for (int j = 0; j < 4; ++j) {
                    int sl = wm * 128 + mf * 16 + g * 4 + j;  // 0..255
                    *(f16*)(T + dl * 512 + ((sl * 2) ^ ((dl & 7) << 4))) =
                        (f16)(acc[mf][nf][j] + bo);
                }
            }
        }
        __syncthreads();
        #pragma unroll
        for (int r = 0; r < 16; ++r) {
            int c = r * 512 + tid;              // 0..8191 chunks of 16B
            int dl = c >> 5, s0 = (c & 31) * 8;
            f16x8 v = *(const f16x8*)(T + dl * 512 + ((s0 * 2) ^ ((dl & 7) << 4)));
            int gcol = bn2 * 256 + dl;          // 0..511
            int head = gcol >> 6, dd = gcol & 63;
            int win = bm * 4 + (s0 >> 6);
            *(f16x8*)(vT + (size_t)win * 32768 + head * 4096 + dd * 64 + (s0 & 63)) = v;
        }
    }
}

// ---------------- attention v3: 4-wave blocks, 16 KB LDS, zero barriers ----------------
// swapped QK^T (S^T = K·Q^T), in-lane softmax, P->reg, transpose via 4KB/head
// half-buffers (2 passes over keys), direct output stores.
__global__ __launch_bounds__(256, 6) void attn_k(
        const f16* __restrict__ qk, const f16* __restrict__ vT,
        f16* __restrict__ attn_h) {
    __shared__ __align__(16) char S[16 * 1024];   // 4 heads x 4 KB half-P
    int tid = threadIdx.x;
    int lane = tid & 63, w = tid >> 6;
    int l15 = lane & 15, g = lane >> 4;
    int win = blockIdx.x >> 1;
    int head = (blockIdx.x & 1) * 4 + w;
    const f16* baseqk = qk + (size_t)win * 65536;
    const f16* basev  = vT + (size_t)win * 32768 + head * 4096;
    int qc = head * 64, kc = 512 + head * 64;

    f32x4 zero4 = {0.f, 0.f, 0.f, 0.f};
    f32x4 acc[4][4];
    #pragma unroll
    for (int a = 0; a < 4; ++a)
        #pragma unroll
        for (int b = 0; b < 4; ++b) acc[a][b] = zero4;

    {   // S^T = K @ Q^T : acc[ki][qi]; row=key=ki*16+g*4+j, col=query=qi*16+l15
        f16x8 qf[4][2], kf[4][2];
        #pragma unroll
        for (int mf = 0; mf < 4; ++mf)
            #pragma unroll
            for (int ks = 0; ks < 2; ++ks)
                qf[mf][ks] = *reinterpret_cast<const f16x8*>(baseqk + (size_t)(mf * 16 + l15) * 1024 + qc + ks * 32 + g * 8);
        #pragma unroll
        for (int nf = 0; nf < 4; ++nf)
            #pragma unroll
            for (int ks = 0; ks < 2; ++ks)
                kf[nf][ks] = *reinterpret_cast<const f16x8*>(baseqk + (size_t)(nf * 16 + l15) * 1024 + kc + ks * 32 + g * 8);
        #pragma unroll
        for (int ks = 0; ks < 2; ++ks)
            #pragma unroll
            for (int ki = 0; ki < 4; ++ki)
                #pragma unroll
                for (int qi = 0; qi < 4; ++qi)
                    acc[ki][qi] = __builtin_amdgcn_mfma_f32_16x16x32_f16(kf[ki][ks], qf[qi][ks], acc[ki][qi], 0, 0, 0);
    }

    // softmax per query: 16 keys in-lane + 2 shfl over g; normalized P stays in acc
    #pragma unroll
    for (int qi = 0; qi < 4; ++qi) {
        float mx = -1e30f;
        #pragma unroll
        for (int ki = 0; ki < 4; ++ki)
            #pragma unroll
            for (int j = 0; j < 4; ++j) mx = fmaxf(mx, acc[ki][qi][j]);
        mx = fmaxf(mx, __shfl_xor(mx, 16));
        mx = fmaxf(mx, __shfl_xor(mx, 32));
        float sum = 0.f;
        #pragma unroll
        for (int ki = 0; ki < 4; ++ki)
            #pragma unroll
            for (int j = 0; j < 4; ++j) {
                float e = __expf((acc[ki][qi][j] - mx) * 0.125f);
                acc[ki][qi][j] = e;
                sum += e;
            }
        sum += __shfl_xor(sum, 16);
        sum += __shfl_xor(sum, 32);
        float rinv = __fdividef(1.0f, sum);
        #pragma unroll
        for (int ki = 0; ki < 4; ++ki)
            #pragma unroll
            for (int j = 0; j < 4; ++j) acc[ki][qi][j] *= rinv;
    }

    // PV in two key-halves through the 4KB half-buffer (wave-local, no barriers)
    char* Sh = S + w * 4096;   // 64 rows x 64 B (32 keys f16), chunk-swizzled
    f32x4 acc2[4][4];
    #pragma unroll
    for (int a = 0; a < 4; ++a)
        #pragma unroll
        for (int b = 0; b < 4; ++b) acc2[a][b] = zero4;

    #pragma unroll
    for (int hf = 0; hf < 2; ++hf) {
        // write P^T half: rows=query, 32 keys
        #pragma unroll
        for (int k2 = 0; k2 < 2; ++k2) {
            int ki = hf * 2 + k2;
            #pragma unroll
            for (int qi = 0; qi < 4; ++qi) {
                int row = qi * 16 + l15;
                char* rowp = Sh + row * 64;
                #pragma unroll
                for (int j = 0; j < 4; ++j) {
                    int kl = k2 * 16 + g * 4 + j;   // 0..31 within half
                    *(f16*)(rowp + ((((kl >> 3) ^ (row & 3)) << 4) | ((kl & 7) * 2))) =
                        (f16)acc[ki][qi][j];
                }
            }
        }
        // V half fragments
        f16x8 vfh[4];
        #pragma unroll
        for (int nf = 0; nf < 4; ++nf)
            vfh[nf] = *reinterpret_cast<const f16x8*>(basev + (nf * 16 + l15) * 64 + hf * 32 + g * 8);
        // read P A-frags + MFMA (acc2 accumulates across halves)
        #pragma unroll
        for (int mf = 0; mf < 4; ++mf) {
            int row = mf * 16 + l15;
            f16x8 pa = *reinterpret_cast<const f16x8*>(Sh + row * 64 + ((g ^ (row & 3)) << 4));
            #pragma unroll
            for (int nf = 0; nf < 4; ++nf)
                acc2[mf][nf] = __builtin_amdgcn_mfma_f32_16x16x32_f16(pa, vfh[nf], acc2[mf][nf], 0, 0, 0);
        }
    }

    // direct output stores (32B/instr granularity, proven non-amplifying)
    f16* dst = attn_h + (size_t)win * 32768 + head * 64;
    #pragma unroll
    for (int mf = 0; mf < 4; ++mf)
        #pragma unroll
        for (int nf = 0; nf < 4; ++nf)
            #pragma unroll
            for (int j = 0; j < 4; ++j)
                dst[(size_t)(mf * 16 + g * 4 + j) * 512 + nf * 16 + l15] = (f16)acc2[mf][nf][j];
}

// ---------------- output projection: single-panel 8-phase GEMM + scatter ----------------
__global__ void __launch_bounds__(512, 2) proj_gemm8_k(
        const f16* __restrict__ attn_h, const f16* __restrict__ Woh,
        const float* __restrict__ b_out, float* __restrict__ out, int nblk, int m0) {
    extern __shared__ f16 lds[];
    int tid = threadIdx.x;
    int lane = tid & 63, wid = tid >> 6;
    int l15 = lane & 15, g = lane >> 4;
    int wm = wid >> 2, wn = wid & 3;
    int sid = (blockIdx.x & 7) * (nblk >> 3) + (blockIdx.x >> 3);
    int bm = sid >> 1, bn = sid & 1;
    const f16* Ap = attn_h + (size_t)bm * 256 * 512;
    const f16* Bp = Woh + (size_t)bn * 256 * 512;

    int li0 = tid, li1 = tid + 512;
    int r0 = li0 >> 3, c0 = li0 & 7, r1 = li1 >> 3, c1 = li1 & 7;
    int off0 = r0 * 512 + ((c0 ^ (r0 & 7)) * 8);
    int off1 = r1 * 512 + ((c1 ^ (r1 & 7)) * 8);

    auto stage = [&](const f16* panel, int ldsbase, int tt, int h) {
        int tb = tt & 1;
        int dst = ldsbase + (tb * 2 + h) * 8192 + wid * 512;
        const f16* src = panel + h * 65536 + tt * 64;
        gload_lds16(src + off0, (void*)&lds[dst]);
        gload_lds16(src + off1, (void*)&lds[dst + 4096]);
    };

    f32x4 acc[8][4];
    f32x4 zero4 = {0.f, 0.f, 0.f, 0.f};
    #pragma unroll
    for (int a = 0; a < 8; ++a)
        #pragma unroll
        for (int b = 0; b < 4; ++b) acc[a][b] = zero4;
    f16x8 bf[4][2];

    stage(Ap, 0, 0, 0); stage(Ap, 0, 0, 1);
    stage(Bp, 32768, 0, 0); stage(Bp, 32768, 0, 1);
    stage(Ap, 0, 1, 0); stage(Ap, 0, 1, 1);
    stage(Bp, 32768, 1, 0); stage(Bp, 32768, 1, 1);
    asm volatile("s_waitcnt vmcnt(8)" ::: "memory");
    __builtin_amdgcn_s_barrier();

    #pragma unroll
    for (int tt = 0; tt < 8; ++tt) {
        int tb = tt & 1;
        const f16* Ab = &lds[(tb * 2 + wm) * 8192];
        const f16* Bb = &lds[32768 + (tb * 2 + (wn >> 1)) * 8192];
        #pragma unroll
        for (int q = 0; q < 4; ++q) {
            f16x8 af[2][2];
            #pragma unroll
            for (int ml = 0; ml < 2; ++ml) {
                int rr = (q * 2 + ml) * 16 + l15;
                #pragma unroll
                for (int ks = 0; ks < 2; ++ks)
                    af[ml][ks] = *(const f16x8*)&Ab[rr * 64 + (((ks * 4 + g) ^ (rr & 7)) * 8)];
            }
            if (q == 0) {
                #pragma unroll
                for (int nf = 0; nf < 4; ++nf) {
                    int rb = (wn & 1) * 64 + nf * 16 + l15;
                    #pragma unroll
                    for (int ks = 0; ks < 2; ++ks)
                        bf[nf][ks] = *(const f16x8*)&Bb[rb * 64 + (((ks * 4 + g) ^ (rb & 7)) * 8)];
                }
            }
            if (q <= 1) {
                if ((tt & 1) ? (tt + 1 < 8) : (tt >= 2)) stage(Ap, 0, tt + 1, q);
            } else {
                if (tt + 2 < 8) stage(Bp, 32768, tt + 2, q - 2);
            }
            __builtin_amdgcn_s_barrier();
            __builtin_amdgcn_s_setprio(1);
            #pragma unroll
            for (int ml = 0; ml < 2; ++ml)
                #pragma unroll
                for (int nf = 0; nf < 4; ++nf)
                    #pragma unroll
                    for (int ks = 0; ks < 2; ++ks)
                        acc[q * 2 + ml][nf] = __builtin_amdgcn_mfma_f32_16x16x32_f16(
                            af[ml][ks], bf[nf][ks], acc[q * 2 + ml][nf], 0, 0, 0);
            __builtin_amdgcn_s_setprio(0);
            if (q == 3) {
                if (tt < 6)       asm volatile("s_waitcnt vmcnt(4)" ::: "memory");
                else if (tt == 6) asm volatile("s_waitcnt vmcnt(0)" ::: "memory");
            }
            __builtin_amdgcn_s_barrier();
        }
    }

    int browg = bm * 256 + wm * 128, bcolg = bn * 256 + wn * 64;
    #pragma unroll
    for (int nf = 0; nf < 4; ++nf) {
        int col = bcolg + nf * 16 + l15;
        float bo = b_out[col];
        #pragma unroll
        for (int mf = 0; mf < 8; ++mf) {
            #pragma unroll
            for (int j = 0; j < 4; ++j) {
                int srow = src_row(m0 + browg + mf * 16 + g * 4 + j);
                out[(size_t)srow * 512 + col] = acc[mf][nf][j] + bo;
            }
        }
    }
}

extern "C" void kernel_launch(void* const* d_in, const int* in_sizes, int n_in,
                              void* d_out, int out_size, void* d_ws, size_t ws_size,
                              hipStream_t stream) {
    (void)in_sizes; (void)n_in; (void)out_size;
    const float* x     = (const float*)d_in[0];
    const float* pos   = (const float*)d_in[1];
    const float* W_in  = (const float*)d_in[2];
    const float* b_in  = (const float*)d_in[3];
    const float* W_out = (const float*)d_in[4];
    const float* b_out = (const float*)d_in[5];
    float* out = (float*)d_out;

    char* ws = (char*)d_ws;
    f16*   Wi_h  = (f16*)ws;                  // 1,572,864 B
    f16*   Wo_h  = (f16*)(ws + 1572864);      //   524,288 B
    float* biasT = (float*)(ws + 2097152);    //   393,216 B
    const size_t fixed = 2490368;

    // 4096 B per row: xh/attn_h (1024, aliased) + qk (2048) + vT (1024).
    // chunks=4 keeps the ~130 MB working set L3-resident (R5-proven).
    int chunks = 4;
    while (chunks < 64) {
        size_t need = fixed + ((size_t)131072 / chunks) * 4096;
        if (need <= ws_size) break;
        chunks <<= 1;
    }
    int Mc = 131072 / chunks;
    f16* xh = (f16*)(ws + fixed);             // also attn_h (xh dead after qkv_gemm)
    f16* qk = (f16*)(ws + fixed + (size_t)Mc * 1024);
    f16* vT = (f16*)(ws + fixed + (size_t)Mc * 3072);
    int nblk  = (Mc / 256) * 6;
    int nblkP = (Mc / 256) * 2;

    static_cast<void>(hipFuncSetAttribute((const void*)qkv_gemm8_k,
        hipFuncAttributeMaxDynamicSharedMemorySize, 131072));
    static_cast<void>(hipFuncSetAttribute((const void*)proj_gemm8_k,
        hipFuncAttributeMaxDynamicSharedMemorySize, 131072));

    prep_weights_k<<<1024, 256, 0, stream>>>(W_in, W_out, Wi_h, Wo_h);
    prep_bias_k<<<384, 256, 0, stream>>>(pos, W_in, b_in, biasT);
    for (int c = 0; c < chunks; ++c) {
        int m0 = c * Mc;
        prep_x_k<<<Mc / 4, 256, 0, stream>>>(x, xh, m0);
        qkv_gemm8_k<<<nblk, 512, 131072, stream>>>(xh, Wi_h, biasT, qk, vT, nblk);
        attn_k<<<(Mc / 64) * 2, 256, 0, stream>>>(qk, vT, xh);
        proj_gemm8_k<<<nblkP, 512, 131072, stream>>>(xh, Wo_h, b_out, out, nblkP, m0);
    }
}

// Round 10
// 581.357 us; speedup vs baseline: 1.9288x; 1.3739x over previous
//
#include <hip/hip_runtime.h>

typedef _Float16 f16;
typedef unsigned int u32;
typedef f16 f16x8 __attribute__((ext_vector_type(8)));
typedef f16 f16x4 __attribute__((ext_vector_type(4)));
typedef float f32x4 __attribute__((ext_vector_type(4)));

// N=4,T=8,H=64,W=64,C=512, WS=8, heads=8, head_dim=64
// windows = 2048, tokens/window = 64, M = 131072, K = 512, Nqkv = 1536

__device__ __forceinline__ int src_row(int m) {
    int win = m >> 6, s = m & 63;
    return ((win >> 6) << 12) | (((win >> 3) & 7) << 9) | ((s >> 3) << 6) |
           ((win & 7) << 3) | (s & 7);
}

__device__ __forceinline__ void gload_lds16(const void* g, void* lds) {
    __builtin_amdgcn_global_load_lds(
        (const __attribute__((address_space(1))) u32*)g,
        (__attribute__((address_space(3))) u32*)lds, 16, 0, 0);
}

// ---------------- prep: weights fp32 -> fp16 ----------------
__global__ __launch_bounds__(256) void prep_weights_k(
        const float* __restrict__ Wi, const float* __restrict__ Wo,
        f16* __restrict__ Wi_h, f16* __restrict__ Wo_h) {
    int i = blockIdx.x * 256 + threadIdx.x;    // 262144 float4s total
    const float4* src;
    f16* dst;
    int idx;
    if (i < 196608) { src = (const float4*)Wi; dst = Wi_h; idx = i; }
    else            { src = (const float4*)Wo; dst = Wo_h; idx = i - 196608; }
    float4 v = src[idx];
    f16x4 h = {(f16)v.x, (f16)v.y, (f16)v.z, (f16)v.w};
    *(f16x4*)(dst + (size_t)idx * 4) = h;
}

// ---------------- prep: biasT[s][o] = b_in[o] + (o<1024 ? pos[s]·W_in[o] : 0)
__global__ __launch_bounds__(256) void prep_bias_k(
        const float* __restrict__ pos, const float* __restrict__ Wi,
        const float* __restrict__ b_in, float* __restrict__ biasT) {
    int idx = blockIdx.x * 256 + threadIdx.x;   // 64*1536
    int s = idx / 1536, o = idx % 1536;
    float acc = b_in[o];
    if (o < 1024) {
        const float4* p4 = (const float4*)(pos + (size_t)s * 512);
        const float4* w4 = (const float4*)(Wi + (size_t)o * 512);
        #pragma unroll 4
        for (int c = 0; c < 128; ++c) {
            float4 a = p4[c], b = w4[c];
            acc += a.x * b.x + a.y * b.y + a.z * b.z + a.w * b.w;
        }
    }
    biasT[idx] = acc;
}

// ---------------- prep: x fp32 -> window-major f16 ----------------
__global__ __launch_bounds__(256) void prep_x_k(
        const float* __restrict__ x, f16* __restrict__ xh, int m0) {
    int i = blockIdx.x * 256 + threadIdx.x;    // Mc*64
    int ml = i >> 6, c8 = (i & 63) * 8;
    int sr = src_row(m0 + ml);
    const float4* s4 = (const float4*)(x + (size_t)sr * 512 + c8);
    float4 a = s4[0], b = s4[1];
    f16x8 hv = {(f16)a.x, (f16)a.y, (f16)a.z, (f16)a.w,
                (f16)b.x, (f16)b.y, (f16)b.z, (f16)b.w};
    *(f16x8*)(xh + (size_t)ml * 512 + c8) = hv;
}

// ---------------- QKV GEMM: 256x256 tile, BK=64, 8-phase counted-vmcnt (R5-proven)
// Q,K cols (bn<4) -> qk[row][0..1023]; V cols (bn>=4) -> vT[win][head][d][s] via LDS transpose
__global__ void __launch_bounds__(512, 2) qkv_gemm8_k(
        const f16* __restrict__ xh, const f16* __restrict__ Wh,
        const float* __restrict__ biasT, f16* __restrict__ qk,
        f16* __restrict__ vT, int nblk) {
    extern __shared__ f16 lds[];
    int tid = threadIdx.x;
    int lane = tid & 63, wid = tid >> 6;
    int l15 = lane & 15, g = lane >> 4;
    int wm = wid >> 2, wn = wid & 3;            // 2M x 4N waves, wave tile 128x64
    int sid = (blockIdx.x & 7) * (nblk >> 3) + (blockIdx.x >> 3);
    int bm = sid / 6, bn = sid % 6;
    const f16* Ap = xh + (size_t)bm * 256 * 512;
    const f16* Bp = Wh + (size_t)bn * 256 * 512;

    int li0 = tid, li1 = tid + 512;
    int r0 = li0 >> 3, c0 = li0 & 7, r1 = li1 >> 3, c1 = li1 & 7;
    int off0 = r0 * 512 + ((c0 ^ (r0 & 7)) * 8);
    int off1 = r1 * 512 + ((c1 ^ (r1 & 7)) * 8);

    auto stage = [&](const f16* panel, int ldsbase, int tt, int h) {
        int tb = tt & 1;
        int dst = ldsbase + (tb * 2 + h) * 8192 + wid * 512;   // wave-uniform
        const f16* src = panel + h * 65536 + tt * 64;
        gload_lds16(src + off0, (void*)&lds[dst]);
        gload_lds16(src + off1, (void*)&lds[dst + 4096]);
    };

    f32x4 acc[8][4];
    f32x4 zero4 = {0.f, 0.f, 0.f, 0.f};
    #pragma unroll
    for (int a = 0; a < 8; ++a)
        #pragma unroll
        for (int b = 0; b < 4; ++b) acc[a][b] = zero4;
    f16x8 bf[4][2];

    stage(Ap, 0, 0, 0); stage(Ap, 0, 0, 1);
    stage(Bp, 32768, 0, 0); stage(Bp, 32768, 0, 1);
    stage(Ap, 0, 1, 0); stage(Ap, 0, 1, 1);
    stage(Bp, 32768, 1, 0); stage(Bp, 32768, 1, 1);
    asm volatile("s_waitcnt vmcnt(0)" ::: "memory");
    __builtin_amdgcn_s_barrier();

    #pragma unroll
    for (int tt = 0; tt < 8; ++tt) {
        int tb = tt & 1;
        const f16* Ab = &lds[(tb * 2 + wm) * 8192];
        const f16* Bb = &lds[32768 + (tb * 2 + (wn >> 1)) * 8192];
        #pragma unroll
        for (int q = 0; q < 4; ++q) {
            f16x8 af[2][2];
            #pragma unroll
            for (int ml = 0; ml < 2; ++ml) {
                int rr = (q * 2 + ml) * 16 + l15;
                #pragma unroll
                for (int ks = 0; ks < 2; ++ks)
                    af[ml][ks] = *(const f16x8*)&Ab[rr * 64 + (((ks * 4 + g) ^ (rr & 7)) * 8)];
            }
            if (q == 0) {
                #pragma unroll
                for (int nf = 0; nf < 4; ++nf) {
                    int rb = (wn & 1) * 64 + nf * 16 + l15;
                    #pragma unroll
                    for (int ks = 0; ks < 2; ++ks)
                        bf[nf][ks] = *(const f16x8*)&Bb[rb * 64 + (((ks * 4 + g) ^ (rb & 7)) * 8)];
                }
            }
            if (q <= 1) {
                if ((tt & 1) ? (tt + 1 < 8) : (tt >= 2)) stage(Ap, 0, tt + 1, q);
            } else {
                if (tt + 2 < 8) stage(Bp, 32768, tt + 2, q - 2);
            }
            __builtin_amdgcn_s_barrier();
            __builtin_amdgcn_s_setprio(1);
            #pragma unroll
            for (int ml = 0; ml < 2; ++ml)
                #pragma unroll
                for (int nf = 0; nf < 4; ++nf)
                    #pragma unroll
                    for (int ks = 0; ks < 2; ++ks)
                        acc[q * 2 + ml][nf] = __builtin_amdgcn_mfma_f32_16x16x32_f16(
                            af[ml][ks], bf[nf][ks], acc[q * 2 + ml][nf], 0, 0, 0);
            __builtin_amdgcn_s_setprio(0);
            if (q == 3) {
                if (tt < 6)       asm volatile("s_waitcnt vmcnt(4)" ::: "memory");
                else if (tt == 6) asm volatile("s_waitcnt vmcnt(0)" ::: "memory");
            }
            __builtin_amdgcn_s_barrier();
        }
    }

    int browg = bm * 256 + wm * 128;
    if (bn < 4) {
        // Q,K: bias (row-dependent) + f16 store, row stride 1024 (proven granularity)
        #pragma unroll
        for (int mf = 0; mf < 8; ++mf) {
            #pragma unroll
            for (int nf = 0; nf < 4; ++nf) {
                int col = bn * 256 + wn * 64 + nf * 16 + l15;
                #pragma unroll
                for (int j = 0; j < 4; ++j) {
                    int row = browg + mf * 16 + g * 4 + j;
                    float v = acc[mf][nf][j] + biasT[(row & 63) * 1536 + col];
                    qk[(size_t)row * 1024 + col] = (f16)v;
                }
            }
        }
    } else {
        // V: bias is row-independent. Transpose via LDS -> vT[win][head][d][s]
        __syncthreads();
        char* T = (char*)lds;   // 256 d-rows x 512 B, XOR-swizzled
        int bn2 = bn - 4;
        #pragma unroll
        for (int mf = 0; mf < 8; ++mf) {
            #pragma unroll
            for (int nf = 0; nf < 4; ++nf) {
                int dl = wn * 64 + nf * 16 + l15;           // 0..255
                float bo = biasT[1024 + bn2 * 256 + dl];
                #pragma unroll
                for (int j = 0; j < 4; ++j) {
                    int sl = wm * 128 + mf * 16 + g * 4 + j;  // 0..255
                    *(f16*)(T + dl * 512 + ((sl * 2) ^ ((dl & 7) << 4))) =
                        (f16)(acc[mf][nf][j] + bo);
                }
            }
        }
        __syncthreads();
        #pragma unroll
        for (int r = 0; r < 16; ++r) {
            int c = r * 512 + tid;              // 0..8191 chunks of 16B
            int dl = c >> 5, s0 = (c & 31) * 8;
            f16x8 v = *(const f16x8*)(T + dl * 512 + ((s0 * 2) ^ ((dl & 7) << 4)));
            int gcol = bn2 * 256 + dl;          // 0..511
            int head = gcol >> 6, dd = gcol & 63;
            int win = bm * 4 + (s0 >> 6);
            *(f16x8*)(vT + (size_t)win * 32768 + head * 4096 + dd * 64 + (s0 & 63)) = v;
        }
    }
}

// ---------------- attention: R5 structure + swapped QK^T in-lane softmax + setprio ----------------
__global__ __launch_bounds__(512) void attn_k(
        const f16* __restrict__ qk, const f16* __restrict__ vT,
        f16* __restrict__ attn_h) {
    __shared__ __align__(16) char S[64 * 1024];   // 8 heads x 8 KB P-slices
    int tid = threadIdx.x;
    int lane = tid & 63, h = tid >> 6;   // wave = head
    int l15 = lane & 15, g = lane >> 4;
    const f16* baseqk = qk + (size_t)blockIdx.x * 65536;
    const f16* basev  = vT + (size_t)blockIdx.x * 32768 + h * 4096;
    int qc = h * 64, kc = 512 + h * 64;

    f32x4 zero4 = {0.f, 0.f, 0.f, 0.f};
    f32x4 acc[4][4];
    #pragma unroll
    for (int a = 0; a < 4; ++a)
        #pragma unroll
        for (int b = 0; b < 4; ++b) acc[a][b] = zero4;

    {   // S^T = K @ Q^T : acc[ki][qi] = S[key=ki*16+g*4+j][query=qi*16+l15]
        f16x8 qf[4][2], kf[4][2];
        #pragma unroll
        for (int mf = 0; mf < 4; ++mf)
            #pragma unroll
            for (int ks = 0; ks < 2; ++ks)
                qf[mf][ks] = *reinterpret_cast<const f16x8*>(baseqk + (size_t)(mf * 16 + l15) * 1024 + qc + ks * 32 + g * 8);
        #pragma unroll
        for (int nf = 0; nf < 4; ++nf)
            #pragma unroll
            for (int ks = 0; ks < 2; ++ks)
                kf[nf][ks] = *reinterpret_cast<const f16x8*>(baseqk + (size_t)(nf * 16 + l15) * 1024 + kc + ks * 32 + g * 8);
        __builtin_amdgcn_s_setprio(1);
        #pragma unroll
        for (int ks = 0; ks < 2; ++ks)
            #pragma unroll
            for (int ki = 0; ki < 4; ++ki)
                #pragma unroll
                for (int qi = 0; qi < 4; ++qi)
                    acc[ki][qi] = __builtin_amdgcn_mfma_f32_16x16x32_f16(kf[ki][ks], qf[qi][ks], acc[ki][qi], 0, 0, 0);
        __builtin_amdgcn_s_setprio(0);
    }

    // V fragments: contiguous f16x8 reads (B-frag: lane holds V[s][d=l15])
    f16x8 vf[4][2];
    #pragma unroll
    for (int nf = 0; nf < 4; ++nf)
        #pragma unroll
        for (int ks = 0; ks < 2; ++ks)
            vf[nf][ks] = *reinterpret_cast<const f16x8*>(basev + (nf * 16 + l15) * 64 + ks * 32 + g * 8);

    // in-lane softmax per query (16 keys in-lane + 2+2 shfl over g); P^T -> LDS [query][key]
    char* Sh = S + h * 8192;
    #pragma unroll
    for (int qi = 0; qi < 4; ++qi) {
        float mx = -1e30f;
        #pragma unroll
        for (int ki = 0; ki < 4; ++ki)
            #pragma unroll
            for (int j = 0; j < 4; ++j) mx = fmaxf(mx, acc[ki][qi][j]);
        mx = fmaxf(mx, __shfl_xor(mx, 16));
        mx = fmaxf(mx, __shfl_xor(mx, 32));
        float sum = 0.f;
        #pragma unroll
        for (int ki = 0; ki < 4; ++ki)
            #pragma unroll
            for (int j = 0; j < 4; ++j) {
                float e = __expf((acc[ki][qi][j] - mx) * 0.125f);
                acc[ki][qi][j] = e;
                sum += e;
            }
        sum += __shfl_xor(sum, 16);
        sum += __shfl_xor(sum, 32);
        float rinv = __fdividef(1.0f, sum);
        int qrow = qi * 16 + l15;
        char* rowp = Sh + qrow * 128;
        int sw = (qrow & 7) << 4;
        #pragma unroll
        for (int ki = 0; ki < 4; ++ki)
            #pragma unroll
            for (int j = 0; j < 4; ++j)
                *(f16*)(rowp + (((ki * 16 + g * 4 + j) * 2) ^ sw)) = (f16)(acc[ki][qi][j] * rinv);
    }

    // out_h = P @ V  (own slice; wave-local, no barrier)
    f32x4 acc2[4][4];
    #pragma unroll
    for (int a = 0; a < 4; ++a)
        #pragma unroll
        for (int b = 0; b < 4; ++b) acc2[a][b] = zero4;
    __builtin_amdgcn_s_setprio(1);
    #pragma unroll
    for (int ks = 0; ks < 2; ++ks)
        #pragma unroll
        for (int mf = 0; mf < 4; ++mf) {
            int rr = mf * 16 + l15;
            f16x8 pa = *reinterpret_cast<const f16x8*>(Sh + rr * 128 + (((ks * 32 + g * 8) * 2) ^ ((rr & 7) << 4)));
            #pragma unroll
            for (int nf = 0; nf < 4; ++nf)
                acc2[mf][nf] = __builtin_amdgcn_mfma_f32_16x16x32_f16(pa, vf[nf][ks], acc2[mf][nf], 0, 0, 0);
        }
    __builtin_amdgcn_s_setprio(0);

    f16* dst = attn_h + (size_t)blockIdx.x * 64 * 512 + h * 64;
    #pragma unroll
    for (int mf = 0; mf < 4; ++mf)
        #pragma unroll
        for (int nf = 0; nf < 4; ++nf)
            #pragma unroll
            for (int j = 0; j < 4; ++j)
                dst[(size_t)(mf * 16 + g * 4 + j) * 512 + nf * 16 + l15] = (f16)acc2[mf][nf][j];
}

// ---------------- output projection: 8-phase 256x256 GEMM + scatter (R5) ----------------
__global__ void __launch_bounds__(512, 2) proj_gemm8_k(
        const f16* __restrict__ attn_h, const f16* __restrict__ Woh,
        const float* __restrict__ b_out, float* __restrict__ out, int nblk, int m0) {
    extern __shared__ f16 lds[];
    int tid = threadIdx.x;
    int lane = tid & 63, wid = tid >> 6;
    int l15 = lane & 15, g = lane >> 4;
    int wm = wid >> 2, wn = wid & 3;
    int sid = (blockIdx.x & 7) * (nblk >> 3) + (blockIdx.x >> 3);
    int bm = sid >> 1, bn = sid & 1;
    const f16* Ap = attn_h + (size_t)bm * 256 * 512;
    const f16* Bp = Woh + (size_t)bn * 256 * 512;

    int li0 = tid, li1 = tid + 512;
    int r0 = li0 >> 3, c0 = li0 & 7, r1 = li1 >> 3, c1 = li1 & 7;
    int off0 = r0 * 512 + ((c0 ^ (r0 & 7)) * 8);
    int off1 = r1 * 512 + ((c1 ^ (r1 & 7)) * 8);

    auto stage = [&](const f16* panel, int ldsbase, int tt, int h) {
        int tb = tt & 1;
        int dst = ldsbase + (tb * 2 + h) * 8192 + wid * 512;
        const f16* src = panel + h * 65536 + tt * 64;
        gload_lds16(src + off0, (void*)&lds[dst]);
        gload_lds16(src + off1, (void*)&lds[dst + 4096]);
    };

    f32x4 acc[8][4];
    f32x4 zero4 = {0.f, 0.f, 0.f, 0.f};
    #pragma unroll
    for (int a = 0; a < 8; ++a)
        #pragma unroll
        for (int b = 0; b < 4; ++b) acc[a][b] = zero4;
    f16x8 bf[4][2];

    stage(Ap, 0, 0, 0); stage(Ap, 0, 0, 1);
    stage(Bp, 32768, 0, 0); stage(Bp, 32768, 0, 1);
    stage(Ap, 0, 1, 0); stage(Ap, 0, 1, 1);
    stage(Bp, 32768, 1, 0); stage(Bp, 32768, 1, 1);
    asm volatile("s_waitcnt vmcnt(0)" ::: "memory");
    __builtin_amdgcn_s_barrier();

    #pragma unroll
    for (int tt = 0; tt < 8; ++tt) {
        int tb = tt & 1;
        const f16* Ab = &lds[(tb * 2 + wm) * 8192];
        const f16* Bb = &lds[32768 + (tb * 2 + (wn >> 1)) * 8192];
        #pragma unroll
        for (int q = 0; q < 4; ++q) {
            f16x8 af[2][2];
            #pragma unroll
            for (int ml = 0; ml < 2; ++ml) {
                int rr = (q * 2 + ml) * 16 + l15;
                #pragma unroll
                for (int ks = 0; ks < 2; ++ks)
                    af[ml][ks] = *(const f16x8*)&Ab[rr * 64 + (((ks * 4 + g) ^ (rr & 7)) * 8)];
            }
            if (q == 0) {
                #pragma unroll
                for (int nf = 0; nf < 4; ++nf) {
                    int rb = (wn & 1) * 64 + nf * 16 + l15;
                    #pragma unroll
                    for (int ks = 0; ks < 2; ++ks)
                        bf[nf][ks] = *(const f16x8*)&Bb[rb * 64 + (((ks * 4 + g) ^ (rb & 7)) * 8)];
                }
            }
            if (q <= 1) {
                if ((tt & 1) ? (tt + 1 < 8) : (tt >= 2)) stage(Ap, 0, tt + 1, q);
            } else {
                if (tt + 2 < 8) stage(Bp, 32768, tt + 2, q - 2);
            }
            __builtin_amdgcn_s_barrier();
            __builtin_amdgcn_s_setprio(1);
            #pragma unroll
            for (int ml = 0; ml < 2; ++ml)
                #pragma unroll
                for (int nf = 0; nf < 4; ++nf)
                    #pragma unroll
                    for (int ks = 0; ks < 2; ++ks)
                        acc[q * 2 + ml][nf] = __builtin_amdgcn_mfma_f32_16x16x32_f16(
                            af[ml][ks], bf[nf][ks], acc[q * 2 + ml][nf], 0, 0, 0);
            __builtin_amdgcn_s_setprio(0);
            if (q == 3) {
                if (tt < 6)       asm volatile("s_waitcnt vmcnt(4)" ::: "memory");
                else if (tt == 6) asm volatile("s_waitcnt vmcnt(0)" ::: "memory");
            }
            __builtin_amdgcn_s_barrier();
        }
    }

    int browg = bm * 256 + wm * 128, bcolg = bn * 256 + wn * 64;
    #pragma unroll
    for (int nf = 0; nf < 4; ++nf) {
        int col = bcolg + nf * 16 + l15;
        float bo = b_out[col];
        #pragma unroll
        for (int mf = 0; mf < 8; ++mf) {
            #pragma unroll
            for (int j = 0; j < 4; ++j) {
                int srow = src_row(m0 + browg + mf * 16 + g * 4 + j);
                out[(size_t)srow * 512 + col] = acc[mf][nf][j] + bo;
            }
        }
    }
}

extern "C" void kernel_launch(void* const* d_in, const int* in_sizes, int n_in,
                              void* d_out, int out_size, void* d_ws, size_t ws_size,
                              hipStream_t stream) {
    (void)in_sizes; (void)n_in; (void)out_size;
    const float* x     = (const float*)d_in[0];
    const float* pos   = (const float*)d_in[1];
    const float* W_in  = (const float*)d_in[2];
    const float* b_in  = (const float*)d_in[3];
    const float* W_out = (const float*)d_in[4];
    const float* b_out = (const float*)d_in[5];
    float* out = (float*)d_out;

    char* ws = (char*)d_ws;
    f16*   Wi_h  = (f16*)ws;                  // 1,572,864 B
    f16*   Wo_h  = (f16*)(ws + 1572864);      //   524,288 B
    float* biasT = (float*)(ws + 2097152);    //   393,216 B
    const size_t fixed = 2490368;

    // 4096 B per row: xh/attn_h (1024, aliased) + qk (2048) + vT (1024).
    // chunks=4 keeps the ~130 MB working set L3-resident (R5-proven).
    int chunks = 4;
    while (chunks < 64) {
        size_t need = fixed + ((size_t)131072 / chunks) * 4096;
        if (need <= ws_size) break;
        chunks <<= 1;
    }
    int Mc = 131072 / chunks;
    f16* xh = (f16*)(ws + fixed);             // also attn_h (xh dead after qkv_gemm)
    f16* qk = (f16*)(ws + fixed + (size_t)Mc * 1024);
    f16* vT = (f16*)(ws + fixed + (size_t)Mc * 3072);
    int nblk  = (Mc / 256) * 6;
    int nblkP = (Mc / 256) * 2;

    static_cast<void>(hipFuncSetAttribute((const void*)qkv_gemm8_k,
        hipFuncAttributeMaxDynamicSharedMemorySize, 131072));
    static_cast<void>(hipFuncSetAttribute((const void*)proj_gemm8_k,
        hipFuncAttributeMaxDynamicSharedMemorySize, 131072));

    prep_weights_k<<<1024, 256, 0, stream>>>(W_in, W_out, Wi_h, Wo_h);
    prep_bias_k<<<384, 256, 0, stream>>>(pos, W_in, b_in, biasT);
    for (int c = 0; c < chunks; ++c) {
        int m0 = c * Mc;
        prep_x_k<<<Mc / 4, 256, 0, stream>>>(x, xh, m0);
        qkv_gemm8_k<<<nblk, 512, 131072, stream>>>(xh, Wi_h, biasT, qk, vT, nblk);
        attn_k<<<Mc / 64, 512, 0, stream>>>(qk, vT, xh);
        proj_gemm8_k<<<nblkP, 512, 131072, stream>>>(xh, Wo_h, b_out, out, nblkP, m0);
    }
}